// Round 2
// baseline (374.675 us; speedup 1.0000x reference)
//
#include <hip/hip_runtime.h>
#include <hip/hip_bf16.h>
#include <math.h>

typedef __bf16 bf16;
typedef __bf16 bf16x8 __attribute__((ext_vector_type(8)));
typedef __bf16 bf16x4 __attribute__((ext_vector_type(4)));
typedef float  f32x4  __attribute__((ext_vector_type(4)));

typedef __attribute__((address_space(1))) void       gvoid;
typedef __attribute__((address_space(3))) void       lvoid;
#define GLOAD_LDS16(gp, lp) __builtin_amdgcn_global_load_lds((gvoid*)(gp), (lvoid*)(lp), 16, 0, 0)

// ---------------------------------------------------------------------------
// fp32 -> bf16 weight conversion (runs every launch; ~75 MB traffic total)
// ---------------------------------------------------------------------------
__global__ __launch_bounds__(256) void cvt_f32_bf16(const float* __restrict__ in,
                                                    bf16* __restrict__ out, int n) {
  int i = (blockIdx.x * 256 + threadIdx.x) * 4;
  if (i < n) {
    f32x4 v = *(const f32x4*)(in + i);
    bf16x4 o;
    #pragma unroll
    for (int e = 0; e < 4; ++e) o[e] = (bf16)v[e];
    *(bf16x4*)(out + i) = o;
  }
}

// ---------------------------------------------------------------------------
// LayerNorm: fp32 in -> bf16 out. One wave per row (C=1024), 16 elems/lane.
// ---------------------------------------------------------------------------
__global__ __launch_bounds__(256) void ln_f32(const float* __restrict__ x,
    const float* __restrict__ g, const float* __restrict__ b, bf16* __restrict__ out) {
  int w = threadIdx.x >> 6, l = threadIdx.x & 63;
  size_t row = (size_t)blockIdx.x * 4 + w;
  const float* xr = x + row * 1024;
  float f[16];
  #pragma unroll
  for (int c = 0; c < 4; ++c) {
    f32x4 v = *(const f32x4*)(xr + c * 256 + l * 4);
    #pragma unroll
    for (int e = 0; e < 4; ++e) f[c * 4 + e] = v[e];
  }
  float s = 0.f, ss = 0.f;
  #pragma unroll
  for (int e = 0; e < 16; ++e) { s += f[e]; ss += f[e] * f[e]; }
  #pragma unroll
  for (int d = 1; d < 64; d <<= 1) { s += __shfl_xor(s, d); ss += __shfl_xor(ss, d); }
  float mean = s * (1.f / 1024.f);
  float var  = ss * (1.f / 1024.f) - mean * mean;
  float rstd = rsqrtf(var + 1e-5f);
  #pragma unroll
  for (int c = 0; c < 4; ++c) {
    f32x4 gv = *(const f32x4*)(g + c * 256 + l * 4);
    f32x4 bv = *(const f32x4*)(b + c * 256 + l * 4);
    bf16x4 ov;
    #pragma unroll
    for (int e = 0; e < 4; ++e)
      ov[e] = (bf16)((f[c * 4 + e] - mean) * rstd * gv[e] + bv[e]);
    *(bf16x4*)(out + row * 1024 + c * 256 + l * 4) = ov;
  }
}

// ---------------------------------------------------------------------------
// m97-structure GEMM: out[M,N] = A[M,K] @ W[N,K]^T (+bias, opt GELU/residual)
// 128x128 tile, BK=32, 4 waves (2x2), global_load_lds width-16 staging.
// A, W bf16; bias fp32; residual fp32; output TO (bf16 or fp32).
// ---------------------------------------------------------------------------
template<int ACT, int HASRES, typename TO>
__global__ __launch_bounds__(256) void gemm_bt(const bf16* __restrict__ A,
    const bf16* __restrict__ W, const float* __restrict__ bias,
    const float* __restrict__ res, TO* __restrict__ out, int M, int N, int K) {
  __shared__ bf16 As[128 * 32];
  __shared__ bf16 Bs[128 * 32];
  int tid = threadIdx.x;
  int w = tid >> 6, l = tid & 63;
  int lr = l & 15, lg = l >> 4;
  int wm = w >> 1, wn = w & 1;
  int rowBase = blockIdx.y * 128;
  int colBase = blockIdx.x * 128;
  f32x4 acc[4][4];
  const f32x4 fz = {0.f, 0.f, 0.f, 0.f};
  #pragma unroll
  for (int i = 0; i < 4; ++i)
    #pragma unroll
    for (int j = 0; j < 4; ++j) acc[i][j] = fz;

  for (int kt = 0; kt < K; kt += 32) {
    __syncthreads();
    #pragma unroll
    for (int j = 0; j < 2; ++j) {
      int u = (w * 2 + j) * 64 + l;          // 0..511 : 16B units of the 8KB tile
      int r = u >> 2, cb = (u & 3) * 8;      // row, col(elem)
      GLOAD_LDS16(A + (size_t)(rowBase + r) * K + kt + cb, As + (w * 2 + j) * 512);
      GLOAD_LDS16(W + (size_t)(colBase + r) * K + kt + cb, Bs + (w * 2 + j) * 512);
    }
    __syncthreads();
    bf16x8 af[4], bfr[4];
    #pragma unroll
    for (int mi = 0; mi < 4; ++mi)
      af[mi] = *(const bf16x8*)(As + (wm * 64 + mi * 16 + lr) * 32 + lg * 8);
    #pragma unroll
    for (int ni = 0; ni < 4; ++ni)
      bfr[ni] = *(const bf16x8*)(Bs + (wn * 64 + ni * 16 + lr) * 32 + lg * 8);
    #pragma unroll
    for (int mi = 0; mi < 4; ++mi)
      #pragma unroll
      for (int ni = 0; ni < 4; ++ni)
        acc[mi][ni] = __builtin_amdgcn_mfma_f32_16x16x32_bf16(af[mi], bfr[ni], acc[mi][ni], 0, 0, 0);
  }

  #pragma unroll
  for (int ni = 0; ni < 4; ++ni) {
    int col = colBase + wn * 64 + ni * 16 + lr;
    float bv = bias[col];
    #pragma unroll
    for (int mi = 0; mi < 4; ++mi) {
      #pragma unroll
      for (int jj = 0; jj < 4; ++jj) {
        int row2 = rowBase + wm * 64 + mi * 16 + lg * 4 + jj;
        float v = acc[mi][ni][jj] + bv;
        if constexpr (ACT == 1) v = 0.5f * v * (1.f + erff(v * 0.70710678118f));
        if constexpr (HASRES)   v += res[(size_t)row2 * N + col];
        out[(size_t)row2 * N + col] = (TO)v;
      }
    }
  }
}

// ---------------------------------------------------------------------------
// Flash attention: grid (N/64, B*H), 4 waves, each wave owns 16 q-rows.
// K tile XOR-swizzled in LDS; V staged transposed (conflict-free row-per-lane
// writes); online softmax via 16-lane shfl reductions; P through per-wave LDS.
// ---------------------------------------------------------------------------
__global__ __launch_bounds__(256) void attn_kernel(const bf16* __restrict__ qkv,
                                                   bf16* __restrict__ o) {
  const int Nn = 2048, C3 = 3072;
  int tid = threadIdx.x, w = tid >> 6, l = tid & 63, lr = l & 15, lg = l >> 4;
  int b = blockIdx.y >> 4, h = blockIdx.y & 15;
  size_t hb = (size_t)b * Nn * C3 + h * 64;
  const bf16* Qp = qkv + hb;
  const bf16* Kp = qkv + hb + 1024;
  const bf16* Vp = qkv + hb + 2048;
  __shared__ bf16 Ks[64 * 64];      // row-major, byte ^= (row&7)<<4 swizzle
  __shared__ bf16 Vt[64 * 72];      // transposed [d][k], pad 72
  __shared__ bf16 Ps[4][16 * 64];   // per-wave P, same XOR swizzle

  int q0 = blockIdx.x * 64 + w * 16;
  bf16x8 qf[2];
  qf[0] = *(const bf16x8*)(Qp + (size_t)(q0 + lr) * C3 + lg * 8);
  qf[1] = *(const bf16x8*)(Qp + (size_t)(q0 + lr) * C3 + 32 + lg * 8);

  const f32x4 fz = {0.f, 0.f, 0.f, 0.f};
  f32x4 oa[4];
  #pragma unroll
  for (int c = 0; c < 4; ++c) oa[c] = fz;
  float mrow[4] = {-1e30f, -1e30f, -1e30f, -1e30f};
  float srow[4] = {0.f, 0.f, 0.f, 0.f};

  for (int t = 0; t < Nn / 64; ++t) {
    size_t k0 = (size_t)t * 64;
    __syncthreads();
    #pragma unroll
    for (int it = 0; it < 2; ++it) {
      int i = it * 256 + tid;
      int kr = i >> 3, c8 = (i & 7) * 8;
      bf16x8 kv = *(const bf16x8*)(Kp + (k0 + kr) * C3 + c8);
      *(bf16x8*)((char*)Ks + kr * 128 + ((c8 * 2) ^ ((kr & 7) << 4))) = kv;
      int vc8 = (it * 4 + w) * 8;                     // wave-uniform d-group
      bf16x8 vv = *(const bf16x8*)(Vp + (k0 + l) * C3 + vc8);
      #pragma unroll
      for (int e = 0; e < 8; ++e) Vt[(vc8 + e) * 72 + l] = vv[e];
    }
    __syncthreads();

    // S = (Q K^T) * 1/8 for this wave's 16 q-rows x 64 keys
    f32x4 sc[4];
    #pragma unroll
    for (int c = 0; c < 4; ++c) {
      f32x4 a = fz;
      #pragma unroll
      for (int kk = 0; kk < 2; ++kk) {
        int krow = c * 16 + lr;
        bf16x8 kf = *(const bf16x8*)((char*)Ks + krow * 128 +
                                     ((kk * 64 + lg * 16) ^ ((krow & 7) << 4)));
        a = __builtin_amdgcn_mfma_f32_16x16x32_bf16(qf[kk], kf, a, 0, 0, 0);
      }
      sc[c] = a * 0.125f;
    }

    // online softmax (row j of this lane's group = lg*4 + j)
    float alpha[4];
    #pragma unroll
    for (int j = 0; j < 4; ++j) {
      float mx = fmaxf(fmaxf(sc[0][j], sc[1][j]), fmaxf(sc[2][j], sc[3][j]));
      #pragma unroll
      for (int d = 1; d < 16; d <<= 1) mx = fmaxf(mx, __shfl_xor(mx, d));
      float mn = fmaxf(mrow[j], mx);
      float al = __expf(mrow[j] - mn);
      float rs = 0.f;
      #pragma unroll
      for (int c = 0; c < 4; ++c) { float p = __expf(sc[c][j] - mn); sc[c][j] = p; rs += p; }
      #pragma unroll
      for (int d = 1; d < 16; d <<= 1) rs += __shfl_xor(rs, d);
      srow[j] = srow[j] * al + rs;
      mrow[j] = mn;
      alpha[j] = al;
    }
    #pragma unroll
    for (int c = 0; c < 4; ++c)
      #pragma unroll
      for (int j = 0; j < 4; ++j) oa[c][j] *= alpha[j];

    // P -> per-wave LDS (bf16, swizzled) so it can be read as MFMA A-fragments
    #pragma unroll
    for (int j = 0; j < 4; ++j) {
      int pr = lg * 4 + j;
      #pragma unroll
      for (int c = 0; c < 4; ++c) {
        int cbyte = ((c * 16 + lr) * 2) ^ ((pr & 7) << 4);
        *(bf16*)((char*)Ps[w] + pr * 128 + cbyte) = (bf16)sc[c][j];
      }
    }
    bf16x8 pf[2];
    #pragma unroll
    for (int kk = 0; kk < 2; ++kk)
      pf[kk] = *(const bf16x8*)((char*)Ps[w] + lr * 128 +
                                ((kk * 64 + lg * 16) ^ ((lr & 7) << 4)));
    // O += P @ V
    #pragma unroll
    for (int c = 0; c < 4; ++c)
      #pragma unroll
      for (int kk = 0; kk < 2; ++kk) {
        bf16x8 vf = *(const bf16x8*)(Vt + (c * 16 + lr) * 72 + kk * 32 + lg * 8);
        oa[c] = __builtin_amdgcn_mfma_f32_16x16x32_bf16(pf[kk], vf, oa[c], 0, 0, 0);
      }
  }

  #pragma unroll
  for (int c = 0; c < 4; ++c)
    #pragma unroll
    for (int j = 0; j < 4; ++j) {
      size_t qr = (size_t)q0 + lg * 4 + j;
      int dc = c * 16 + lr;
      float v = oa[c][j] / srow[j];
      o[((size_t)b * Nn + qr) * 1024 + h * 64 + dc] = (bf16)v;
    }
}

// ---------------------------------------------------------------------------
extern "C" void kernel_launch(void* const* d_in, const int* in_sizes, int n_in,
                              void* d_out, int out_size, void* d_ws, size_t ws_size,
                              hipStream_t stream) {
  (void)in_sizes; (void)n_in; (void)out_size; (void)ws_size;
  const float* x     = (const float*)d_in[0];
  const float* ln1g  = (const float*)d_in[1];
  const float* ln1b  = (const float*)d_in[2];
  const float* qkvw  = (const float*)d_in[3];
  const float* qkvb  = (const float*)d_in[4];
  const float* projw = (const float*)d_in[5];
  const float* projb = (const float*)d_in[6];
  const float* ln2g  = (const float*)d_in[7];
  const float* ln2b  = (const float*)d_in[8];
  const float* fc1w  = (const float*)d_in[9];
  const float* fc1b  = (const float*)d_in[10];
  const float* fc2w  = (const float*)d_in[11];
  const float* fc2b  = (const float*)d_in[12];

  char* ws = (char*)d_ws;
  bf16*  qkvw_h = (bf16*)(ws);                    // [0,  6M)
  bf16*  projw_h= (bf16*)(ws + (6ull  << 20));    // [6,  8M)
  bf16*  fc1w_h = (bf16*)(ws + (8ull  << 20));    // [8, 16M)
  bf16*  fc2w_h = (bf16*)(ws + (16ull << 20));    // [16,24M)
  bf16*  h1     = (bf16*)(ws + (24ull << 20));    // [24,32M)  (reused for h2)
  bf16*  qkv    = (bf16*)(ws + (32ull << 20));    // [32,64M)  (reused for ffn)
  bf16*  ov     = (bf16*)(ws + (64ull << 20));    // [64,72M)
  float* x1     = (float*)(ws + (72ull << 20));   // [72,88M)  fp32 residual trunk
  bf16*  h2  = h1;
  bf16*  ffn = qkv;

  const int M = 4096;
  cvt_f32_bf16<<<dim3(3145728 / 1024), 256, 0, stream>>>(qkvw, qkvw_h, 3145728);
  cvt_f32_bf16<<<dim3(1048576 / 1024), 256, 0, stream>>>(projw, projw_h, 1048576);
  cvt_f32_bf16<<<dim3(4194304 / 1024), 256, 0, stream>>>(fc1w, fc1w_h, 4194304);
  cvt_f32_bf16<<<dim3(4194304 / 1024), 256, 0, stream>>>(fc2w, fc2w_h, 4194304);

  ln_f32<<<dim3(M / 4), 256, 0, stream>>>(x, ln1g, ln1b, h1);
  gemm_bt<0, 0, bf16><<<dim3(3072 / 128, M / 128), 256, 0, stream>>>(
      h1, qkvw_h, qkvb, (const float*)nullptr, qkv, M, 3072, 1024);
  attn_kernel<<<dim3(2048 / 64, 32), 256, 0, stream>>>(qkv, ov);
  gemm_bt<0, 1, float><<<dim3(1024 / 128, M / 128), 256, 0, stream>>>(
      ov, projw_h, projb, x, x1, M, 1024, 1024);
  ln_f32<<<dim3(M / 4), 256, 0, stream>>>(x1, ln2g, ln2b, h2);
  gemm_bt<1, 0, bf16><<<dim3(4096 / 128, M / 128), 256, 0, stream>>>(
      h2, fc1w_h, fc1b, (const float*)nullptr, ffn, M, 4096, 1024);
  gemm_bt<0, 1, float><<<dim3(1024 / 128, M / 128), 256, 0, stream>>>(
      ffn, fc2w_h, fc2b, x1, (float*)d_out, M, 1024, 4096);
}

// Round 3
// 332.801 us; speedup vs baseline: 1.1258x; 1.1258x over previous
//
#include <hip/hip_runtime.h>
#include <hip/hip_bf16.h>
#include <math.h>

typedef __bf16 bf16;
typedef __bf16 bf16x8 __attribute__((ext_vector_type(8)));
typedef __bf16 bf16x4 __attribute__((ext_vector_type(4)));
typedef float  f32x4  __attribute__((ext_vector_type(4)));

typedef __attribute__((address_space(1))) void       gvoid;
typedef __attribute__((address_space(3))) void       lvoid;
#define GLOAD_LDS16(gp, lp) __builtin_amdgcn_global_load_lds((gvoid*)(gp), (lvoid*)(lp), 16, 0, 0)

// ---------------------------------------------------------------------------
// fused fp32 -> bf16 weight conversion (single launch, 12.58M elems)
// blocks: [0,3072) qkvw | [3072,4096) projw | [4096,8192) fc1w | [8192,12288) fc2w
// ---------------------------------------------------------------------------
__global__ __launch_bounds__(256) void cvt_all(const float* __restrict__ a,
    const float* __restrict__ b, const float* __restrict__ c,
    const float* __restrict__ d, bf16* __restrict__ oa, bf16* __restrict__ ob,
    bf16* __restrict__ oc, bf16* __restrict__ od) {
  int blk = blockIdx.x;
  const float* in; bf16* out; int base;
  if (blk < 3072)      { in = a; out = oa; base = blk; }
  else if (blk < 4096) { in = b; out = ob; base = blk - 3072; }
  else if (blk < 8192) { in = c; out = oc; base = blk - 4096; }
  else                 { in = d; out = od; base = blk - 8192; }
  int i = (base * 256 + threadIdx.x) * 4;
  f32x4 v = *(const f32x4*)(in + i);
  bf16x4 o;
  #pragma unroll
  for (int e = 0; e < 4; ++e) o[e] = (bf16)v[e];
  *(bf16x4*)(out + i) = o;
}

// ---------------------------------------------------------------------------
// LayerNorm: fp32 in -> bf16 out. One wave per row (C=1024), 16 elems/lane.
// ---------------------------------------------------------------------------
__global__ __launch_bounds__(256) void ln_f32(const float* __restrict__ x,
    const float* __restrict__ g, const float* __restrict__ b, bf16* __restrict__ out) {
  int w = threadIdx.x >> 6, l = threadIdx.x & 63;
  size_t row = (size_t)blockIdx.x * 4 + w;
  const float* xr = x + row * 1024;
  float f[16];
  #pragma unroll
  for (int c = 0; c < 4; ++c) {
    f32x4 v = *(const f32x4*)(xr + c * 256 + l * 4);
    #pragma unroll
    for (int e = 0; e < 4; ++e) f[c * 4 + e] = v[e];
  }
  float s = 0.f, ss = 0.f;
  #pragma unroll
  for (int e = 0; e < 16; ++e) { s += f[e]; ss += f[e] * f[e]; }
  #pragma unroll
  for (int d = 1; d < 64; d <<= 1) { s += __shfl_xor(s, d); ss += __shfl_xor(ss, d); }
  float mean = s * (1.f / 1024.f);
  float var  = ss * (1.f / 1024.f) - mean * mean;
  float rstd = rsqrtf(var + 1e-5f);
  #pragma unroll
  for (int c = 0; c < 4; ++c) {
    f32x4 gv = *(const f32x4*)(g + c * 256 + l * 4);
    f32x4 bv = *(const f32x4*)(b + c * 256 + l * 4);
    bf16x4 ov;
    #pragma unroll
    for (int e = 0; e < 4; ++e)
      ov[e] = (bf16)((f[c * 4 + e] - mean) * rstd * gv[e] + bv[e]);
    *(bf16x4*)(out + row * 1024 + c * 256 + l * 4) = ov;
  }
}

// ---------------------------------------------------------------------------
// m97-structure GEMM: out[M,N] = A[M,K] @ W[N,K]^T (+bias, opt GELU/residual)
// ---------------------------------------------------------------------------
template<int ACT, int HASRES, typename TO>
__global__ __launch_bounds__(256) void gemm_bt(const bf16* __restrict__ A,
    const bf16* __restrict__ W, const float* __restrict__ bias,
    const float* __restrict__ res, TO* __restrict__ out, int M, int N, int K) {
  __shared__ bf16 As[128 * 32];
  __shared__ bf16 Bs[128 * 32];
  int tid = threadIdx.x;
  int w = tid >> 6, l = tid & 63;
  int lr = l & 15, lg = l >> 4;
  int wm = w >> 1, wn = w & 1;
  int rowBase = blockIdx.y * 128;
  int colBase = blockIdx.x * 128;
  f32x4 acc[4][4];
  const f32x4 fz = {0.f, 0.f, 0.f, 0.f};
  #pragma unroll
  for (int i = 0; i < 4; ++i)
    #pragma unroll
    for (int j = 0; j < 4; ++j) acc[i][j] = fz;

  for (int kt = 0; kt < K; kt += 32) {
    __syncthreads();
    #pragma unroll
    for (int j = 0; j < 2; ++j) {
      int u = (w * 2 + j) * 64 + l;
      int r = u >> 2, cb = (u & 3) * 8;
      GLOAD_LDS16(A + (size_t)(rowBase + r) * K + kt + cb, As + (w * 2 + j) * 512);
      GLOAD_LDS16(W + (size_t)(colBase + r) * K + kt + cb, Bs + (w * 2 + j) * 512);
    }
    __syncthreads();
    bf16x8 af[4], bfr[4];
    #pragma unroll
    for (int mi = 0; mi < 4; ++mi)
      af[mi] = *(const bf16x8*)(As + (wm * 64 + mi * 16 + lr) * 32 + lg * 8);
    #pragma unroll
    for (int ni = 0; ni < 4; ++ni)
      bfr[ni] = *(const bf16x8*)(Bs + (wn * 64 + ni * 16 + lr) * 32 + lg * 8);
    #pragma unroll
    for (int mi = 0; mi < 4; ++mi)
      #pragma unroll
      for (int ni = 0; ni < 4; ++ni)
        acc[mi][ni] = __builtin_amdgcn_mfma_f32_16x16x32_bf16(af[mi], bfr[ni], acc[mi][ni], 0, 0, 0);
  }

  #pragma unroll
  for (int ni = 0; ni < 4; ++ni) {
    int col = colBase + wn * 64 + ni * 16 + lr;
    float bv = bias[col];
    #pragma unroll
    for (int mi = 0; mi < 4; ++mi) {
      #pragma unroll
      for (int jj = 0; jj < 4; ++jj) {
        int row2 = rowBase + wm * 64 + mi * 16 + lg * 4 + jj;
        float v = acc[mi][ni][jj] + bv;
        if constexpr (ACT == 1) v = 0.5f * v * (1.f + erff(v * 0.70710678118f));
        if constexpr (HASRES)   v += res[(size_t)row2 * N + col];
        out[(size_t)row2 * N + col] = (TO)v;
      }
    }
  }
}

// ---------------------------------------------------------------------------
// Flash attention v2: swapped QK^T (lane owns one q-row) -> tree+2-shfl
// softmax, vectorized P path (4x ds_write_b64), swapped PV (O^T = V^T P^T),
// T14 next-tile register prefetch, XCD-aware block swizzle.
// grid: 1024 blocks (32 qb x 32 bh), 4 waves, 16 q-rows/wave.
// ---------------------------------------------------------------------------
__global__ __launch_bounds__(256) void attn_kernel(const bf16* __restrict__ qkv,
                                                   bf16* __restrict__ o) {
  const int Nn = 2048, C3 = 3072;
  int tid = threadIdx.x, w = tid >> 6, l = tid & 63, lr = l & 15, lg = l >> 4;
  // XCD swizzle: 1024 blocks = 8 XCDs x 128; contiguous wg-chunk per XCD
  int lin = blockIdx.x;
  int wg = (lin & 7) * 128 + (lin >> 3);
  int qb = wg & 31, bh = wg >> 5;
  int b = bh >> 4, h = bh & 15;
  size_t hb = (size_t)b * Nn * C3 + h * 64;
  const bf16* Qp = qkv + hb;
  const bf16* Kp = qkv + hb + 1024;
  const bf16* Vp = qkv + hb + 2048;
  __shared__ bf16 Ks[64 * 64];      // row-major, byte ^= (row&7)<<4 swizzle
  __shared__ bf16 Vt[64 * 72];      // transposed [d][k], pad 72
  __shared__ bf16 Ps[4][16 * 64];   // per-wave P[q][k], byte ^= (q&7)<<4

  int q0 = qb * 64 + w * 16;
  // B-operand Q fragments, pre-scaled by 1/8 (exact in bf16)
  bf16x8 qf[2];
  #pragma unroll
  for (int kk = 0; kk < 2; ++kk) {
    bf16x8 t = *(const bf16x8*)(Qp + (size_t)(q0 + lr) * C3 + kk * 32 + lg * 8);
    #pragma unroll
    for (int e = 0; e < 8; ++e) qf[kk][e] = (bf16)((float)t[e] * 0.125f);
  }

  const f32x4 fz = {0.f, 0.f, 0.f, 0.f};
  f32x4 oa[4];                      // O^T: lane holds O[q=lr][d=cd*16+4*lg+j]
  #pragma unroll
  for (int c = 0; c < 4; ++c) oa[c] = fz;
  float mrow = -1e30f, srow = 0.f;

  int kr0 = tid >> 3,        c80 = (tid & 7) * 8;
  int kr1 = (256 + tid) >> 3, c81 = (tid & 7) * 8;   // rows 32..63
  bf16x8 kreg0, kreg1, vreg0, vreg1;
  // prefetch tile 0
  kreg0 = *(const bf16x8*)(Kp + (size_t)kr0 * C3 + c80);
  kreg1 = *(const bf16x8*)(Kp + (size_t)kr1 * C3 + c81);
  vreg0 = *(const bf16x8*)(Vp + (size_t)l * C3 + w * 8);
  vreg1 = *(const bf16x8*)(Vp + (size_t)l * C3 + (4 + w) * 8);

  for (int t = 0; t < Nn / 64; ++t) {
    __syncthreads();   // previous tile's compute fully done
    *(bf16x8*)((char*)Ks + kr0 * 128 + ((c80 * 2) ^ ((kr0 & 7) << 4))) = kreg0;
    *(bf16x8*)((char*)Ks + kr1 * 128 + ((c81 * 2) ^ ((kr1 & 7) << 4))) = kreg1;
    #pragma unroll
    for (int e = 0; e < 8; ++e) Vt[(w * 8 + e) * 72 + l]       = vreg0[e];
    #pragma unroll
    for (int e = 0; e < 8; ++e) Vt[((4 + w) * 8 + e) * 72 + l] = vreg1[e];
    __syncthreads();
    if (t + 1 < Nn / 64) {          // T14: issue next-tile loads, hide under compute
      size_t kn = (size_t)(t + 1) * 64;
      kreg0 = *(const bf16x8*)(Kp + (kn + kr0) * C3 + c80);
      kreg1 = *(const bf16x8*)(Kp + (kn + kr1) * C3 + c81);
      vreg0 = *(const bf16x8*)(Vp + (kn + l) * C3 + w * 8);
      vreg1 = *(const bf16x8*)(Vp + (kn + l) * C3 + (4 + w) * 8);
    }

    // S^T = K Q^T (scaled): lane holds S[q=lr][k=16c+4lg+j]
    f32x4 sc[4];
    #pragma unroll
    for (int c = 0; c < 4; ++c) {
      f32x4 a = fz;
      #pragma unroll
      for (int kk = 0; kk < 2; ++kk) {
        int krow = c * 16 + lr;
        bf16x8 kf = *(const bf16x8*)((char*)Ks + krow * 128 +
                                     ((kk * 64 + lg * 16) ^ ((krow & 7) << 4)));
        a = __builtin_amdgcn_mfma_f32_16x16x32_bf16(kf, qf[kk], a, 0, 0, 0);
      }
      sc[c] = a;
    }

    // online softmax: per-lane tree over 16 values + 2 shfl (q-row = lr)
    float m0 = fmaxf(fmaxf(sc[0][0], sc[0][1]), fmaxf(sc[0][2], sc[0][3]));
    float m1 = fmaxf(fmaxf(sc[1][0], sc[1][1]), fmaxf(sc[1][2], sc[1][3]));
    float m2 = fmaxf(fmaxf(sc[2][0], sc[2][1]), fmaxf(sc[2][2], sc[2][3]));
    float m3 = fmaxf(fmaxf(sc[3][0], sc[3][1]), fmaxf(sc[3][2], sc[3][3]));
    float mt = fmaxf(fmaxf(m0, m1), fmaxf(m2, m3));
    mt = fmaxf(mt, __shfl_xor(mt, 16));
    mt = fmaxf(mt, __shfl_xor(mt, 32));
    float mn = fmaxf(mrow, mt);
    float al = __expf(mrow - mn);
    float p[4][4];
    float rs = 0.f;
    #pragma unroll
    for (int c = 0; c < 4; ++c) {
      float r0 = __expf(sc[c][0] - mn), r1 = __expf(sc[c][1] - mn);
      float r2 = __expf(sc[c][2] - mn), r3 = __expf(sc[c][3] - mn);
      p[c][0] = r0; p[c][1] = r1; p[c][2] = r2; p[c][3] = r3;
      rs += (r0 + r1) + (r2 + r3);
    }
    rs += __shfl_xor(rs, 16);
    rs += __shfl_xor(rs, 32);
    srow = srow * al + rs;
    mrow = mn;
    #pragma unroll
    for (int c = 0; c < 4; ++c)
      #pragma unroll
      for (int j = 0; j < 4; ++j) oa[c][j] *= al;

    // P -> per-wave LDS: 4x ds_write_b64 (k-contiguous), swizzled by q-row
    #pragma unroll
    for (int c = 0; c < 4; ++c) {
      bf16x4 pk;
      #pragma unroll
      for (int j = 0; j < 4; ++j) pk[j] = (bf16)p[c][j];
      *(bf16x4*)((char*)Ps[w] + lr * 128 + ((c * 32 + lg * 8) ^ ((lr & 7) << 4))) = pk;
    }
    bf16x8 pb[2];
    #pragma unroll
    for (int kk = 0; kk < 2; ++kk)
      pb[kk] = *(const bf16x8*)((char*)Ps[w] + lr * 128 +
                                ((kk * 64 + lg * 16) ^ ((lr & 7) << 4)));
    // O^T += V^T P^T
    #pragma unroll
    for (int cd = 0; cd < 4; ++cd)
      #pragma unroll
      for (int kk = 0; kk < 2; ++kk) {
        bf16x8 vf = *(const bf16x8*)(Vt + (cd * 16 + lr) * 72 + kk * 32 + lg * 8);
        oa[cd] = __builtin_amdgcn_mfma_f32_16x16x32_bf16(vf, pb[kk], oa[cd], 0, 0, 0);
      }
  }

  float inv = 1.f / srow;
  #pragma unroll
  for (int cd = 0; cd < 4; ++cd)
    #pragma unroll
    for (int j = 0; j < 4; ++j) {
      size_t qr = (size_t)q0 + lr;
      int dc = cd * 16 + lg * 4 + j;
      o[((size_t)b * Nn + qr) * 1024 + h * 64 + dc] = (bf16)(oa[cd][j] * inv);
    }
}

// ---------------------------------------------------------------------------
extern "C" void kernel_launch(void* const* d_in, const int* in_sizes, int n_in,
                              void* d_out, int out_size, void* d_ws, size_t ws_size,
                              hipStream_t stream) {
  (void)in_sizes; (void)n_in; (void)out_size; (void)ws_size;
  const float* x     = (const float*)d_in[0];
  const float* ln1g  = (const float*)d_in[1];
  const float* ln1b  = (const float*)d_in[2];
  const float* qkvw  = (const float*)d_in[3];
  const float* qkvb  = (const float*)d_in[4];
  const float* projw = (const float*)d_in[5];
  const float* projb = (const float*)d_in[6];
  const float* ln2g  = (const float*)d_in[7];
  const float* ln2b  = (const float*)d_in[8];
  const float* fc1w  = (const float*)d_in[9];
  const float* fc1b  = (const float*)d_in[10];
  const float* fc2w  = (const float*)d_in[11];
  const float* fc2b  = (const float*)d_in[12];

  char* ws = (char*)d_ws;
  bf16*  qkvw_h = (bf16*)(ws);                    // [0,  6M)
  bf16*  projw_h= (bf16*)(ws + (6ull  << 20));    // [6,  8M)
  bf16*  fc1w_h = (bf16*)(ws + (8ull  << 20));    // [8, 16M)
  bf16*  fc2w_h = (bf16*)(ws + (16ull << 20));    // [16,24M)
  bf16*  h1     = (bf16*)(ws + (24ull << 20));    // [24,32M)  (reused for h2)
  bf16*  qkv    = (bf16*)(ws + (32ull << 20));    // [32,64M)  (reused for ffn)
  bf16*  ov     = (bf16*)(ws + (64ull << 20));    // [64,72M)
  float* x1     = (float*)(ws + (72ull << 20));   // [72,88M)  fp32 residual trunk
  bf16*  h2  = h1;
  bf16*  ffn = qkv;

  const int M = 4096;
  cvt_all<<<dim3(12288), 256, 0, stream>>>(qkvw, projw, fc1w, fc2w,
                                           qkvw_h, projw_h, fc1w_h, fc2w_h);
  ln_f32<<<dim3(M / 4), 256, 0, stream>>>(x, ln1g, ln1b, h1);
  gemm_bt<0, 0, bf16><<<dim3(3072 / 128, M / 128), 256, 0, stream>>>(
      h1, qkvw_h, qkvb, (const float*)nullptr, qkv, M, 3072, 1024);
  attn_kernel<<<dim3(1024), 256, 0, stream>>>(qkv, ov);
  gemm_bt<0, 1, float><<<dim3(1024 / 128, M / 128), 256, 0, stream>>>(
      ov, projw_h, projb, x, x1, M, 1024, 1024);
  ln_f32<<<dim3(M / 4), 256, 0, stream>>>(x1, ln2g, ln2b, h2);
  gemm_bt<1, 0, bf16><<<dim3(4096 / 128, M / 128), 256, 0, stream>>>(
      h2, fc1w_h, fc1b, (const float*)nullptr, ffn, M, 4096, 1024);
  gemm_bt<0, 1, float><<<dim3(1024 / 128, M / 128), 256, 0, stream>>>(
      ffn, fc2w_h, fc2b, x1, (float*)d_out, M, 1024, 4096);
}

// Round 5
// 316.725 us; speedup vs baseline: 1.1830x; 1.0508x over previous
//
#include <hip/hip_runtime.h>
#include <hip/hip_bf16.h>
#include <math.h>

typedef __bf16 bf16;
typedef __bf16 bf16x8 __attribute__((ext_vector_type(8)));
typedef __bf16 bf16x4 __attribute__((ext_vector_type(4)));
typedef float  f32x4  __attribute__((ext_vector_type(4)));

typedef __attribute__((address_space(1))) void gvoid;
typedef __attribute__((address_space(3))) void lvoid;
#define GLOAD_LDS16(gp, lp) __builtin_amdgcn_global_load_lds((gvoid*)(gp), (lvoid*)(lp), 16, 0, 0)

// ---------------------------------------------------------------------------
// prep: fused weight fp32->bf16 conversion (blocks 0..12287) + LN1 (12288+)
// ---------------------------------------------------------------------------
__global__ __launch_bounds__(256) void prep(
    const float* __restrict__ qkvw, const float* __restrict__ projw,
    const float* __restrict__ fc1w, const float* __restrict__ fc2w,
    bf16* __restrict__ qkvw_h, bf16* __restrict__ projw_h,
    bf16* __restrict__ fc1w_h, bf16* __restrict__ fc2w_h,
    const float* __restrict__ x, const float* __restrict__ g,
    const float* __restrict__ b, bf16* __restrict__ h1) {
  int blk = blockIdx.x;
  if (blk < 12288) {
    const float* in; bf16* out; int base;
    if (blk < 3072)      { in = qkvw; out = qkvw_h; base = blk; }
    else if (blk < 4096) { in = projw; out = projw_h; base = blk - 3072; }
    else if (blk < 8192) { in = fc1w; out = fc1w_h; base = blk - 4096; }
    else                 { in = fc2w; out = fc2w_h; base = blk - 8192; }
    int i = (base * 256 + threadIdx.x) * 4;
    f32x4 v = *(const f32x4*)(in + i);
    bf16x4 o;
    #pragma unroll
    for (int e = 0; e < 4; ++e) o[e] = (bf16)v[e];
    *(bf16x4*)(out + i) = o;
    return;
  }
  int w = threadIdx.x >> 6, l = threadIdx.x & 63;
  size_t row = (size_t)(blk - 12288) * 4 + w;
  const float* xr = x + row * 1024;
  float f[16];
  #pragma unroll
  for (int c = 0; c < 4; ++c) {
    f32x4 v = *(const f32x4*)(xr + c * 256 + l * 4);
    #pragma unroll
    for (int e = 0; e < 4; ++e) f[c * 4 + e] = v[e];
  }
  float s = 0.f, ss = 0.f;
  #pragma unroll
  for (int e = 0; e < 16; ++e) { s += f[e]; ss += f[e] * f[e]; }
  #pragma unroll
  for (int d = 1; d < 64; d <<= 1) { s += __shfl_xor(s, d); ss += __shfl_xor(ss, d); }
  float mean = s * (1.f / 1024.f);
  float var  = ss * (1.f / 1024.f) - mean * mean;
  float rstd = rsqrtf(var + 1e-5f);
  #pragma unroll
  for (int c = 0; c < 4; ++c) {
    f32x4 gv = *(const f32x4*)(g + c * 256 + l * 4);
    f32x4 bv = *(const f32x4*)(b + c * 256 + l * 4);
    bf16x4 ov;
    #pragma unroll
    for (int e = 0; e < 4; ++e)
      ov[e] = (bf16)((f[c * 4 + e] - mean) * rstd * gv[e] + bv[e]);
    *(bf16x4*)(h1 + row * 1024 + c * 256 + l * 4) = ov;
  }
}

// ---------------------------------------------------------------------------
// LayerNorm standalone (for LN2): fp32 in -> bf16 out.
// ---------------------------------------------------------------------------
__global__ __launch_bounds__(256) void ln_f32(const float* __restrict__ x,
    const float* __restrict__ g, const float* __restrict__ b, bf16* __restrict__ out) {
  int w = threadIdx.x >> 6, l = threadIdx.x & 63;
  size_t row = (size_t)blockIdx.x * 4 + w;
  const float* xr = x + row * 1024;
  float f[16];
  #pragma unroll
  for (int c = 0; c < 4; ++c) {
    f32x4 v = *(const f32x4*)(xr + c * 256 + l * 4);
    #pragma unroll
    for (int e = 0; e < 4; ++e) f[c * 4 + e] = v[e];
  }
  float s = 0.f, ss = 0.f;
  #pragma unroll
  for (int e = 0; e < 16; ++e) { s += f[e]; ss += f[e] * f[e]; }
  #pragma unroll
  for (int d = 1; d < 64; d <<= 1) { s += __shfl_xor(s, d); ss += __shfl_xor(ss, d); }
  float mean = s * (1.f / 1024.f);
  float var  = ss * (1.f / 1024.f) - mean * mean;
  float rstd = rsqrtf(var + 1e-5f);
  #pragma unroll
  for (int c = 0; c < 4; ++c) {
    f32x4 gv = *(const f32x4*)(g + c * 256 + l * 4);
    f32x4 bv = *(const f32x4*)(b + c * 256 + l * 4);
    bf16x4 ov;
    #pragma unroll
    for (int e = 0; e < 4; ++e)
      ov[e] = (bf16)((f[c * 4 + e] - mean) * rstd * gv[e] + bv[e]);
    *(bf16x4*)(out + row * 1024 + c * 256 + l * 4) = ov;
  }
}

// ---------------------------------------------------------------------------
// 8-phase 256x256 GEMM (T2+T3+T4+T5): out[M,N] = A[M,K] @ W[N,K]^T + bias.
// 512 thr (8 waves 2Mx4N), BK=64, 128KB LDS double-buffered, st_16x32 swizzle
// (linear global_load_lds dest + pre-swizzled source + swizzled ds_read),
// counted vmcnt(4) at phases 4/8 only, setprio(1) around MFMA clusters.
// Halves = consumption stripes: A row-bit6 (offset bit13), B row-bit5 (bit12).
// FIX(r5): LDS dest must be the half-INSERTED offset tb_ (physical == ttp_),
// so that physical[p] = global[SWZ(p)] and swizzled reads invert correctly.
// ---------------------------------------------------------------------------
#define SWZ(tp) ((tp) ^ ((((tp) >> 9) & 1) << 5))
#define STAGE(buf, op, half, kt_) do { \
    const char* gp_ = (const char*)((op) ? Wp : Ap); \
    int t0_ = (op) ? colBase : rowBase; \
    const int P_ = (op) ? 12 : 13; \
    _Pragma("unroll") for (int s_ = 0; s_ < 2; ++s_) { \
      int b14_ = w * 2048 + s_ * 1024; \
      int tb_ = ((b14_ >> P_) << (P_ + 1)) | ((half) << P_) | (b14_ & ((1 << P_) - 1)); \
      int tq_ = SWZ(tb_ + l * 16); \
      GLOAD_LDS16(gp_ + ((size_t)(t0_ + (tq_ >> 7)) * K + (size_t)(kt_) * 64) * 2 + (tq_ & 127), \
                  smbase + (buf) * 65536 + (op) * 32768 + tb_); \
    } \
  } while (0)
#define LDA(buf, mi, kk) (*(const bf16x8*)(smbase + (buf) * 65536 + \
    SWZ((wm * 128 + (mi) * 16 + lr) * 128 + (kk) * 64 + lg * 16)))
#define LDB(buf, ni, kk) (*(const bf16x8*)(smbase + (buf) * 65536 + 32768 + \
    SWZ((wn * 64 + (ni) * 16 + lr) * 128 + (kk) * 64 + lg * 16)))
#define RD_A(buf, MI0) { _Pragma("unroll") for (int i_ = 0; i_ < 4; ++i_) \
    _Pragma("unroll") for (int k_ = 0; k_ < 2; ++k_) a[i_][k_] = LDA(buf, (MI0) + i_, k_); }
#define RD_B(buf, NI0) { _Pragma("unroll") for (int j_ = 0; j_ < 2; ++j_) \
    _Pragma("unroll") for (int k_ = 0; k_ < 2; ++k_) bq[j_][k_] = LDB(buf, (NI0) + j_, k_); }
#define MFMA16(MI0, NI0) do { __builtin_amdgcn_s_setprio(1); \
    _Pragma("unroll") for (int i_ = 0; i_ < 4; ++i_) \
    _Pragma("unroll") for (int j_ = 0; j_ < 2; ++j_) \
    _Pragma("unroll") for (int k_ = 0; k_ < 2; ++k_) \
      acc[(MI0) + i_][(NI0) + j_] = __builtin_amdgcn_mfma_f32_16x16x32_bf16( \
          a[i_][k_], bq[j_][k_], acc[(MI0) + i_][(NI0) + j_], 0, 0, 0); \
    __builtin_amdgcn_s_setprio(0); } while (0)
#define BARX() __builtin_amdgcn_s_barrier()
#define LGK0() asm volatile("s_waitcnt lgkmcnt(0)")
#define VM4()  asm volatile("s_waitcnt vmcnt(4)")

template<int ACT>
__global__ __launch_bounds__(512, 2) void gemm256(const bf16* __restrict__ Ap,
    const bf16* __restrict__ Wp, const float* __restrict__ bias,
    bf16* __restrict__ out, int M, int N, int K, int nbx) {
  __shared__ bf16 smem_[2][2][256 * 64];
  char* smbase = (char*)smem_;
  int tid = threadIdx.x, w = tid >> 6, l = tid & 63, lr = l & 15, lg = l >> 4;
  int wm = w >> 2, wn = w & 3;
  int q = gridDim.x >> 3;                       // grid %8 == 0 for all our shapes
  int wg = ((int)blockIdx.x & 7) * q + ((int)blockIdx.x >> 3);
  int rowBase = (wg / nbx) * 256, colBase = (wg % nbx) * 256;

  f32x4 acc[8][4];
  const f32x4 fz = {0.f, 0.f, 0.f, 0.f};
  #pragma unroll
  for (int i = 0; i < 8; ++i)
    #pragma unroll
    for (int j = 0; j < 4; ++j) acc[i][j] = fz;
  bf16x8 a[4][2], bq[2][2];
  int nkt = K >> 6;

  // prologue: tile0 fully, then Blo(1), Ahi(1) -> leaves exactly 2 halves in flight
  STAGE(0, 0, 0, 0); STAGE(0, 1, 0, 0); STAGE(0, 0, 1, 0); STAGE(0, 1, 1, 0);
  STAGE(1, 1, 0, 1); STAGE(1, 0, 1, 1);
  VM4(); BARX();

  for (int t = 0; t < nkt; t += 2) {
    int t1 = t + 1;
    int t2 = t + 2 < nkt ? t + 2 : nkt - 1;
    int t3 = t + 3 < nkt ? t + 3 : nkt - 1;
    // ph1: Q(0,0) of tile t; stage Alo(t+1),Bhi(t+1)->buf1 (buf1 regions dead)
    RD_A(0, 0); RD_B(0, 0);
    STAGE(1, 0, 0, t1); STAGE(1, 1, 1, t1);
    BARX(); LGK0(); MFMA16(0, 0); BARX();
    // ph2: Q(4,0)
    RD_A(0, 4);
    BARX(); LGK0(); MFMA16(4, 0); BARX();
    // ph3: Q(4,2); stage Blo(t+2)->buf0 (B-lo last read ph1)
    RD_B(0, 2);
    STAGE(0, 1, 0, t2);
    BARX(); LGK0(); MFMA16(4, 2); BARX();
    // ph4: Q(0,2); stage Ahi(t+2)->buf0 (A-hi last read ph2); vmcnt -> t1 landed
    RD_A(0, 0);
    STAGE(0, 0, 1, t2);
    VM4();
    BARX(); LGK0(); MFMA16(0, 2); BARX();
    // ph5: Q(0,0) of tile t+1 (buf1); stage Alo(t+2),Bhi(t+2)->buf0
    RD_A(1, 0); RD_B(1, 0);
    STAGE(0, 0, 0, t2); STAGE(0, 1, 1, t2);
    BARX(); LGK0(); MFMA16(0, 0); BARX();
    // ph6
    RD_A(1, 4);
    BARX(); LGK0(); MFMA16(4, 0); BARX();
    // ph7: stage Blo(t+3)->buf1
    RD_B(1, 2);
    STAGE(1, 1, 0, t3);
    BARX(); LGK0(); MFMA16(4, 2); BARX();
    // ph8: stage Ahi(t+3)->buf1; vmcnt -> t2 landed
    RD_A(1, 0);
    STAGE(1, 0, 1, t3);
    VM4();
    BARX(); LGK0(); MFMA16(0, 2); BARX();
  }

  #pragma unroll
  for (int ni = 0; ni < 4; ++ni) {
    int col = colBase + wn * 64 + ni * 16 + lr;
    float bv = bias[col];
    #pragma unroll
    for (int mi = 0; mi < 8; ++mi) {
      #pragma unroll
      for (int jj = 0; jj < 4; ++jj) {
        int row2 = rowBase + wm * 128 + mi * 16 + lg * 4 + jj;
        float v = acc[mi][ni][jj] + bv;
        if constexpr (ACT == 1) v = 0.5f * v * (1.f + erff(v * 0.70710678118f));
        out[(size_t)row2 * N + col] = (bf16)v;
      }
    }
  }
}

// ---------------------------------------------------------------------------
// m97-structure GEMM (kept for proj & FC2: grids too small for 256^2 tiles)
// ---------------------------------------------------------------------------
template<int ACT, int HASRES, typename TO>
__global__ __launch_bounds__(256) void gemm_bt(const bf16* __restrict__ A,
    const bf16* __restrict__ W, const float* __restrict__ bias,
    const float* __restrict__ res, TO* __restrict__ out, int M, int N, int K) {
  __shared__ bf16 As[128 * 32];
  __shared__ bf16 Bs[128 * 32];
  int tid = threadIdx.x;
  int w = tid >> 6, l = tid & 63;
  int lr = l & 15, lg = l >> 4;
  int wm = w >> 1, wn = w & 1;
  int rowBase = blockIdx.y * 128;
  int colBase = blockIdx.x * 128;
  f32x4 acc[4][4];
  const f32x4 fz = {0.f, 0.f, 0.f, 0.f};
  #pragma unroll
  for (int i = 0; i < 4; ++i)
    #pragma unroll
    for (int j = 0; j < 4; ++j) acc[i][j] = fz;

  for (int kt = 0; kt < K; kt += 32) {
    __syncthreads();
    #pragma unroll
    for (int j = 0; j < 2; ++j) {
      int u = (w * 2 + j) * 64 + l;
      int r = u >> 2, cb = (u & 3) * 8;
      GLOAD_LDS16(A + (size_t)(rowBase + r) * K + kt + cb, As + (w * 2 + j) * 512);
      GLOAD_LDS16(W + (size_t)(colBase + r) * K + kt + cb, Bs + (w * 2 + j) * 512);
    }
    __syncthreads();
    bf16x8 af[4], bfr[4];
    #pragma unroll
    for (int mi = 0; mi < 4; ++mi)
      af[mi] = *(const bf16x8*)(As + (wm * 64 + mi * 16 + lr) * 32 + lg * 8);
    #pragma unroll
    for (int ni = 0; ni < 4; ++ni)
      bfr[ni] = *(const bf16x8*)(Bs + (wn * 64 + ni * 16 + lr) * 32 + lg * 8);
    #pragma unroll
    for (int mi = 0; mi < 4; ++mi)
      #pragma unroll
      for (int ni = 0; ni < 4; ++ni)
        acc[mi][ni] = __builtin_amdgcn_mfma_f32_16x16x32_bf16(af[mi], bfr[ni], acc[mi][ni], 0, 0, 0);
  }

  #pragma unroll
  for (int ni = 0; ni < 4; ++ni) {
    int col = colBase + wn * 64 + ni * 16 + lr;
    float bv = bias[col];
    #pragma unroll
    for (int mi = 0; mi < 4; ++mi) {
      #pragma unroll
      for (int jj = 0; jj < 4; ++jj) {
        int row2 = rowBase + wm * 64 + mi * 16 + lg * 4 + jj;
        float v = acc[mi][ni][jj] + bv;
        if constexpr (ACT == 1) v = 0.5f * v * (1.f + erff(v * 0.70710678118f));
        if constexpr (HASRES)   v += res[(size_t)row2 * N + col];
        out[(size_t)row2 * N + col] = (TO)v;
      }
    }
  }
}

// ---------------------------------------------------------------------------
// Flash attention: swapped QK^T, exp2-domain online softmax (log2e folded into
// Q prescale), defer-max (T13), setprio (T5), T14 prefetch, XCD swizzle.
// ---------------------------------------------------------------------------
__global__ __launch_bounds__(256) void attn_kernel(const bf16* __restrict__ qkv,
                                                   bf16* __restrict__ o) {
  const int Nn = 2048, C3 = 3072;
  int tid = threadIdx.x, w = tid >> 6, l = tid & 63, lr = l & 15, lg = l >> 4;
  int lin = blockIdx.x;
  int wg = (lin & 7) * 128 + (lin >> 3);
  int qb = wg & 31, bh = wg >> 5;
  int b = bh >> 4, h = bh & 15;
  size_t hb = (size_t)b * Nn * C3 + h * 64;
  const bf16* Qp = qkv + hb;
  const bf16* Kp = qkv + hb + 1024;
  const bf16* Vp = qkv + hb + 2048;
  __shared__ bf16 Ks[64 * 64];
  __shared__ bf16 Vt[64 * 72];
  __shared__ bf16 Ps[4][16 * 64];

  int q0 = qb * 64 + w * 16;
  // Q prescale: (1/8) * log2(e) so softmax runs in exp2 domain
  bf16x8 qf[2];
  #pragma unroll
  for (int kk = 0; kk < 2; ++kk) {
    bf16x8 t = *(const bf16x8*)(Qp + (size_t)(q0 + lr) * C3 + kk * 32 + lg * 8);
    #pragma unroll
    for (int e = 0; e < 8; ++e) qf[kk][e] = (bf16)((float)t[e] * 0.18033688f);
  }

  const f32x4 fz = {0.f, 0.f, 0.f, 0.f};
  f32x4 oa[4];
  #pragma unroll
  for (int c = 0; c < 4; ++c) oa[c] = fz;
  float mrow = -1e30f, srow = 0.f;

  int kr0 = tid >> 3,         c80 = (tid & 7) * 8;
  int kr1 = (256 + tid) >> 3, c81 = (tid & 7) * 8;
  bf16x8 kreg0, kreg1, vreg0, vreg1;
  kreg0 = *(const bf16x8*)(Kp + (size_t)kr0 * C3 + c80);
  kreg1 = *(const bf16x8*)(Kp + (size_t)kr1 * C3 + c81);
  vreg0 = *(const bf16x8*)(Vp + (size_t)l * C3 + w * 8);
  vreg1 = *(const bf16x8*)(Vp + (size_t)l * C3 + (4 + w) * 8);

  for (int t = 0; t < Nn / 64; ++t) {
    __syncthreads();
    *(bf16x8*)((char*)Ks + kr0 * 128 + ((c80 * 2) ^ ((kr0 & 7) << 4))) = kreg0;
    *(bf16x8*)((char*)Ks + kr1 * 128 + ((c81 * 2) ^ ((kr1 & 7) << 4))) = kreg1;
    #pragma unroll
    for (int e = 0; e < 8; ++e) Vt[(w * 8 + e) * 72 + l]       = vreg0[e];
    #pragma unroll
    for (int e = 0; e < 8; ++e) Vt[((4 + w) * 8 + e) * 72 + l] = vreg1[e];
    __syncthreads();
    if (t + 1 < Nn / 64) {
      size_t kn = (size_t)(t + 1) * 64;
      kreg0 = *(const bf16x8*)(Kp + (kn + kr0) * C3 + c80);
      kreg1 = *(const bf16x8*)(Kp + (kn + kr1) * C3 + c81);
      vreg0 = *(const bf16x8*)(Vp + (kn + l) * C3 + w * 8);
      vreg1 = *(const bf16x8*)(Vp + (kn + l) * C3 + (4 + w) * 8);
    }

    // S^T = K Q^T (log2-scaled): lane holds S[q=lr][k=16c+4lg+j]
    f32x4 sc[4];
    __builtin_amdgcn_s_setprio(1);
    #pragma unroll
    for (int c = 0; c < 4; ++c) {
      f32x4 acm = fz;
      #pragma unroll
      for (int kk = 0; kk < 2; ++kk) {
        int krow = c * 16 + lr;
        bf16x8 kf = *(const bf16x8*)((char*)Ks + krow * 128 +
                                     ((kk * 64 + lg * 16) ^ ((krow & 7) << 4)));
        acm = __builtin_amdgcn_mfma_f32_16x16x32_bf16(kf, qf[kk], acm, 0, 0, 0);
      }
      sc[c] = acm;
    }
    __builtin_amdgcn_s_setprio(0);

    // online softmax in exp2 domain, defer-max (THR=8 log2-units)
    float m0 = fmaxf(fmaxf(sc[0][0], sc[0][1]), fmaxf(sc[0][2], sc[0][3]));
    float m1 = fmaxf(fmaxf(sc[1][0], sc[1][1]), fmaxf(sc[1][2], sc[1][3]));
    float m2 = fmaxf(fmaxf(sc[2][0], sc[2][1]), fmaxf(sc[2][2], sc[2][3]));
    float m3 = fmaxf(fmaxf(sc[3][0], sc[3][1]), fmaxf(sc[3][2], sc[3][3]));
    float mt = fmaxf(fmaxf(m0, m1), fmaxf(m2, m3));
    mt = fmaxf(mt, __shfl_xor(mt, 16));
    mt = fmaxf(mt, __shfl_xor(mt, 32));
    if (!__all(mt - mrow <= 8.f)) {
      float mn = fmaxf(mrow, mt);
      float al = exp2f(mrow - mn);
      mrow = mn;
      srow *= al;
      #pragma unroll
      for (int c = 0; c < 4; ++c)
        #pragma unroll
        for (int j = 0; j < 4; ++j) oa[c][j] *= al;
    }
    float p[4][4];
    float rs = 0.f;
    #pragma unroll
    for (int c = 0; c < 4; ++c) {
      float r0 = exp2f(sc[c][0] - mrow), r1 = exp2f(sc[c][1] - mrow);
      float r2 = exp2f(sc[c][2] - mrow), r3 = exp2f(sc[c][3] - mrow);
      p[c][0] = r0; p[c][1] = r1; p[c][2] = r2; p[c][3] = r3;
      rs += (r0 + r1) + (r2 + r3);
    }
    rs += __shfl_xor(rs, 16);
    rs += __shfl_xor(rs, 32);
    srow += rs;

    #pragma unroll
    for (int c = 0; c < 4; ++c) {
      bf16x4 pk;
      #pragma unroll
      for (int j = 0; j < 4; ++j) pk[j] = (bf16)p[c][j];
      *(bf16x4*)((char*)Ps[w] + lr * 128 + ((c * 32 + lg * 8) ^ ((lr & 7) << 4))) = pk;
    }
    bf16x8 pb[2];
    #pragma unroll
    for (int kk = 0; kk < 2; ++kk)
      pb[kk] = *(const bf16x8*)((char*)Ps[w] + lr * 128 +
                                ((kk * 64 + lg * 16) ^ ((lr & 7) << 4)));
    __builtin_amdgcn_s_setprio(1);
    #pragma unroll
    for (int cd = 0; cd < 4; ++cd)
      #pragma unroll
      for (int kk = 0; kk < 2; ++kk) {
        bf16x8 vf = *(const bf16x8*)(Vt + (cd * 16 + lr) * 72 + kk * 32 + lg * 8);
        oa[cd] = __builtin_amdgcn_mfma_f32_16x16x32_bf16(vf, pb[kk], oa[cd], 0, 0, 0);
      }
    __builtin_amdgcn_s_setprio(0);
  }

  float inv = 1.f / srow;
  #pragma unroll
  for (int cd = 0; cd < 4; ++cd)
    #pragma unroll
    for (int j = 0; j < 4; ++j) {
      size_t qr = (size_t)q0 + lr;
      int dc = cd * 16 + lg * 4 + j;
      o[((size_t)b * Nn + qr) * 1024 + h * 64 + dc] = (bf16)(oa[cd][j] * inv);
    }
}

// ---------------------------------------------------------------------------
extern "C" void kernel_launch(void* const* d_in, const int* in_sizes, int n_in,
                              void* d_out, int out_size, void* d_ws, size_t ws_size,
                              hipStream_t stream) {
  (void)in_sizes; (void)n_in; (void)out_size; (void)ws_size;
  const float* x     = (const float*)d_in[0];
  const float* ln1g  = (const float*)d_in[1];
  const float* ln1b  = (const float*)d_in[2];
  const float* qkvw  = (const float*)d_in[3];
  const float* qkvb  = (const float*)d_in[4];
  const float* projw = (const float*)d_in[5];
  const float* projb = (const float*)d_in[6];
  const float* ln2g  = (const float*)d_in[7];
  const float* ln2b  = (const float*)d_in[8];
  const float* fc1w  = (const float*)d_in[9];
  const float* fc1b  = (const float*)d_in[10];
  const float* fc2w  = (const float*)d_in[11];
  const float* fc2b  = (const float*)d_in[12];

  char* ws = (char*)d_ws;
  bf16*  qkvw_h = (bf16*)(ws);                    // [0,  6M)
  bf16*  projw_h= (bf16*)(ws + (6ull  << 20));    // [6,  8M)
  bf16*  fc1w_h = (bf16*)(ws + (8ull  << 20));    // [8, 16M)
  bf16*  fc2w_h = (bf16*)(ws + (16ull << 20));    // [16,24M)
  bf16*  h1     = (bf16*)(ws + (24ull << 20));    // [24,32M)  (reused for h2)
  bf16*  qkv    = (bf16*)(ws + (32ull << 20));    // [32,64M)  (reused for ffn)
  bf16*  ov     = (bf16*)(ws + (64ull << 20));    // [64,72M)
  float* x1     = (float*)(ws + (72ull << 20));   // [72,88M)  fp32 residual trunk
  bf16*  h2  = h1;
  bf16*  ffn = qkv;

  const int M = 4096;
  prep<<<dim3(12288 + 1024), 256, 0, stream>>>(qkvw, projw, fc1w, fc2w,
      qkvw_h, projw_h, fc1w_h, fc2w_h, x, ln1g, ln1b, h1);
  gemm256<0><<<dim3(192), dim3(512), 0, stream>>>(
      h1, qkvw_h, qkvb, qkv, M, 3072, 1024, 12);
  attn_kernel<<<dim3(1024), 256, 0, stream>>>(qkv, ov);
  gemm_bt<0, 1, float><<<dim3(1024 / 128, M / 128), 256, 0, stream>>>(
      ov, projw_h, projb, x, x1, M, 1024, 1024);
  ln_f32<<<dim3(M / 4), 256, 0, stream>>>(x1, ln2g, ln2b, h2);
  gemm256<1><<<dim3(256), dim3(512), 0, stream>>>(
      h2, fc1w_h, fc1b, ffn, M, 4096, 1024, 16);
  gemm_bt<0, 1, float><<<dim3(1024 / 128, M / 128), 256, 0, stream>>>(
      ffn, fc2w_h, fc2b, x1, (float*)d_out, M, 1024, 4096);
}

// Round 6
// 299.221 us; speedup vs baseline: 1.2522x; 1.0585x over previous
//
#include <hip/hip_runtime.h>
#include <hip/hip_bf16.h>
#include <math.h>

typedef __bf16 bf16;
typedef __bf16 bf16x8 __attribute__((ext_vector_type(8)));
typedef __bf16 bf16x4 __attribute__((ext_vector_type(4)));
typedef float  f32x4  __attribute__((ext_vector_type(4)));

typedef __attribute__((address_space(1))) void gvoid;
typedef __attribute__((address_space(3))) void lvoid;
#define GLOAD_LDS16(gp, lp) __builtin_amdgcn_global_load_lds((gvoid*)(gp), (lvoid*)(lp), 16, 0, 0)

// ---------------------------------------------------------------------------
// prep: fused weight fp32->bf16 conversion (blocks 0..12287) + LN1 (12288+)
// ---------------------------------------------------------------------------
__global__ __launch_bounds__(256) void prep(
    const float* __restrict__ qkvw, const float* __restrict__ projw,
    const float* __restrict__ fc1w, const float* __restrict__ fc2w,
    bf16* __restrict__ qkvw_h, bf16* __restrict__ projw_h,
    bf16* __restrict__ fc1w_h, bf16* __restrict__ fc2w_h,
    const float* __restrict__ x, const float* __restrict__ g,
    const float* __restrict__ b, bf16* __restrict__ h1) {
  int blk = blockIdx.x;
  if (blk < 12288) {
    const float* in; bf16* out; int base;
    if (blk < 3072)      { in = qkvw; out = qkvw_h; base = blk; }
    else if (blk < 4096) { in = projw; out = projw_h; base = blk - 3072; }
    else if (blk < 8192) { in = fc1w; out = fc1w_h; base = blk - 4096; }
    else                 { in = fc2w; out = fc2w_h; base = blk - 8192; }
    int i = (base * 256 + threadIdx.x) * 4;
    f32x4 v = *(const f32x4*)(in + i);
    bf16x4 o;
    #pragma unroll
    for (int e = 0; e < 4; ++e) o[e] = (bf16)v[e];
    *(bf16x4*)(out + i) = o;
    return;
  }
  int w = threadIdx.x >> 6, l = threadIdx.x & 63;
  size_t row = (size_t)(blk - 12288) * 4 + w;
  const float* xr = x + row * 1024;
  float f[16];
  #pragma unroll
  for (int c = 0; c < 4; ++c) {
    f32x4 v = *(const f32x4*)(xr + c * 256 + l * 4);
    #pragma unroll
    for (int e = 0; e < 4; ++e) f[c * 4 + e] = v[e];
  }
  float s = 0.f, ss = 0.f;
  #pragma unroll
  for (int e = 0; e < 16; ++e) { s += f[e]; ss += f[e] * f[e]; }
  #pragma unroll
  for (int d = 1; d < 64; d <<= 1) { s += __shfl_xor(s, d); ss += __shfl_xor(ss, d); }
  float mean = s * (1.f / 1024.f);
  float var  = ss * (1.f / 1024.f) - mean * mean;
  float rstd = rsqrtf(var + 1e-5f);
  #pragma unroll
  for (int c = 0; c < 4; ++c) {
    f32x4 gv = *(const f32x4*)(g + c * 256 + l * 4);
    f32x4 bv = *(const f32x4*)(b + c * 256 + l * 4);
    bf16x4 ov;
    #pragma unroll
    for (int e = 0; e < 4; ++e)
      ov[e] = (bf16)((f[c * 4 + e] - mean) * rstd * gv[e] + bv[e]);
    *(bf16x4*)(h1 + row * 1024 + c * 256 + l * 4) = ov;
  }
}

// ---------------------------------------------------------------------------
// LayerNorm standalone (for LN2): fp32 in -> bf16 out.
// ---------------------------------------------------------------------------
__global__ __launch_bounds__(256) void ln_f32(const float* __restrict__ x,
    const float* __restrict__ g, const float* __restrict__ b, bf16* __restrict__ out) {
  int w = threadIdx.x >> 6, l = threadIdx.x & 63;
  size_t row = (size_t)blockIdx.x * 4 + w;
  const float* xr = x + row * 1024;
  float f[16];
  #pragma unroll
  for (int c = 0; c < 4; ++c) {
    f32x4 v = *(const f32x4*)(xr + c * 256 + l * 4);
    #pragma unroll
    for (int e = 0; e < 4; ++e) f[c * 4 + e] = v[e];
  }
  float s = 0.f, ss = 0.f;
  #pragma unroll
  for (int e = 0; e < 16; ++e) { s += f[e]; ss += f[e] * f[e]; }
  #pragma unroll
  for (int d = 1; d < 64; d <<= 1) { s += __shfl_xor(s, d); ss += __shfl_xor(ss, d); }
  float mean = s * (1.f / 1024.f);
  float var  = ss * (1.f / 1024.f) - mean * mean;
  float rstd = rsqrtf(var + 1e-5f);
  #pragma unroll
  for (int c = 0; c < 4; ++c) {
    f32x4 gv = *(const f32x4*)(g + c * 256 + l * 4);
    f32x4 bv = *(const f32x4*)(b + c * 256 + l * 4);
    bf16x4 ov;
    #pragma unroll
    for (int e = 0; e < 4; ++e)
      ov[e] = (bf16)((f[c * 4 + e] - mean) * rstd * gv[e] + bv[e]);
    *(bf16x4*)(out + row * 1024 + c * 256 + l * 4) = ov;
  }
}

// ---------------------------------------------------------------------------
// 8-phase 256x256 GEMM (T2+T3+T4+T5). Generalized (r6): lda row stride,
// klen loop length, optional K-slice via blockIdx.y (Ap/Wp advance by
// y*klen, out by y*outSlice), TO output type, HASBIAS flag. Sync schedule
// identical to the r5-verified template.
// ---------------------------------------------------------------------------
#define SWZ(tp) ((tp) ^ ((((tp) >> 9) & 1) << 5))
#define STAGE(buf, op, half, kt_) do { \
    const char* gp_ = (const char*)((op) ? Wp : Ap); \
    int t0_ = (op) ? colBase : rowBase; \
    const int P_ = (op) ? 12 : 13; \
    _Pragma("unroll") for (int s_ = 0; s_ < 2; ++s_) { \
      int b14_ = w * 2048 + s_ * 1024; \
      int tb_ = ((b14_ >> P_) << (P_ + 1)) | ((half) << P_) | (b14_ & ((1 << P_) - 1)); \
      int tq_ = SWZ(tb_ + l * 16); \
      GLOAD_LDS16(gp_ + ((size_t)(t0_ + (tq_ >> 7)) * lda + (size_t)(kt_) * 64) * 2 + (tq_ & 127), \
                  smbase + (buf) * 65536 + (op) * 32768 + tb_); \
    } \
  } while (0)
#define LDA(buf, mi, kk) (*(const bf16x8*)(smbase + (buf) * 65536 + \
    SWZ((wm * 128 + (mi) * 16 + lr) * 128 + (kk) * 64 + lg * 16)))
#define LDB(buf, ni, kk) (*(const bf16x8*)(smbase + (buf) * 65536 + 32768 + \
    SWZ((wn * 64 + (ni) * 16 + lr) * 128 + (kk) * 64 + lg * 16)))
#define RD_A(buf, MI0) { _Pragma("unroll") for (int i_ = 0; i_ < 4; ++i_) \
    _Pragma("unroll") for (int k_ = 0; k_ < 2; ++k_) a[i_][k_] = LDA(buf, (MI0) + i_, k_); }
#define RD_B(buf, NI0) { _Pragma("unroll") for (int j_ = 0; j_ < 2; ++j_) \
    _Pragma("unroll") for (int k_ = 0; k_ < 2; ++k_) bq[j_][k_] = LDB(buf, (NI0) + j_, k_); }
#define MFMA16(MI0, NI0) do { __builtin_amdgcn_s_setprio(1); \
    _Pragma("unroll") for (int i_ = 0; i_ < 4; ++i_) \
    _Pragma("unroll") for (int j_ = 0; j_ < 2; ++j_) \
    _Pragma("unroll") for (int k_ = 0; k_ < 2; ++k_) \
      acc[(MI0) + i_][(NI0) + j_] = __builtin_amdgcn_mfma_f32_16x16x32_bf16( \
          a[i_][k_], bq[j_][k_], acc[(MI0) + i_][(NI0) + j_], 0, 0, 0); \
    __builtin_amdgcn_s_setprio(0); } while (0)
#define BARX() __builtin_amdgcn_s_barrier()
#define LGK0() asm volatile("s_waitcnt lgkmcnt(0)")
#define VM4()  asm volatile("s_waitcnt vmcnt(4)")

template<int ACT, int HASBIAS, typename TO>
__global__ __launch_bounds__(512, 2) void gemm256(const bf16* __restrict__ Ap,
    const bf16* __restrict__ Wp, const float* __restrict__ bias,
    TO* __restrict__ out, int lda, int N, int klen, int nbx, size_t outSlice) {
  __shared__ bf16 smem_[2][2][256 * 64];
  char* smbase = (char*)smem_;
  int tid = threadIdx.x, w = tid >> 6, l = tid & 63, lr = l & 15, lg = l >> 4;
  int wm = w >> 2, wn = w & 3;
  int q = gridDim.x >> 3;                       // grid.x % 8 == 0 for all our shapes
  int wg = ((int)blockIdx.x & 7) * q + ((int)blockIdx.x >> 3);
  int rowBase = (wg / nbx) * 256, colBase = (wg % nbx) * 256;
  Ap += (size_t)blockIdx.y * klen;
  Wp += (size_t)blockIdx.y * klen;
  out += (size_t)blockIdx.y * outSlice;

  f32x4 acc[8][4];
  const f32x4 fz = {0.f, 0.f, 0.f, 0.f};
  #pragma unroll
  for (int i = 0; i < 8; ++i)
    #pragma unroll
    for (int j = 0; j < 4; ++j) acc[i][j] = fz;
  bf16x8 a[4][2], bq[2][2];
  int nkt = klen >> 6;

  // prologue: tile0 fully, then Blo(1), Ahi(1) -> leaves exactly 2 halves in flight
  STAGE(0, 0, 0, 0); STAGE(0, 1, 0, 0); STAGE(0, 0, 1, 0); STAGE(0, 1, 1, 0);
  STAGE(1, 1, 0, 1); STAGE(1, 0, 1, 1);
  VM4(); BARX();

  for (int t = 0; t < nkt; t += 2) {
    int t1 = t + 1;
    int t2 = t + 2 < nkt ? t + 2 : nkt - 1;
    int t3 = t + 3 < nkt ? t + 3 : nkt - 1;
    RD_A(0, 0); RD_B(0, 0);
    STAGE(1, 0, 0, t1); STAGE(1, 1, 1, t1);
    BARX(); LGK0(); MFMA16(0, 0); BARX();
    RD_A(0, 4);
    BARX(); LGK0(); MFMA16(4, 0); BARX();
    RD_B(0, 2);
    STAGE(0, 1, 0, t2);
    BARX(); LGK0(); MFMA16(4, 2); BARX();
    RD_A(0, 0);
    STAGE(0, 0, 1, t2);
    VM4();
    BARX(); LGK0(); MFMA16(0, 2); BARX();
    RD_A(1, 0); RD_B(1, 0);
    STAGE(0, 0, 0, t2); STAGE(0, 1, 1, t2);
    BARX(); LGK0(); MFMA16(0, 0); BARX();
    RD_A(1, 4);
    BARX(); LGK0(); MFMA16(4, 0); BARX();
    RD_B(1, 2);
    STAGE(1, 1, 0, t3);
    BARX(); LGK0(); MFMA16(4, 2); BARX();
    RD_A(1, 0);
    STAGE(1, 0, 1, t3);
    VM4();
    BARX(); LGK0(); MFMA16(0, 2); BARX();
  }

  #pragma unroll
  for (int ni = 0; ni < 4; ++ni) {
    int col = colBase + wn * 64 + ni * 16 + lr;
    float bv = HASBIAS ? bias[col] : 0.f;
    #pragma unroll
    for (int mi = 0; mi < 8; ++mi) {
      #pragma unroll
      for (int jj = 0; jj < 4; ++jj) {
        int row2 = rowBase + wm * 128 + mi * 16 + lg * 4 + jj;
        float v = acc[mi][ni][jj] + bv;
        if constexpr (ACT == 1) v = 0.5f * v * (1.f + erff(v * 0.70710678118f));
        out[(size_t)row2 * N + col] = (TO)v;
      }
    }
  }
}

// ---------------------------------------------------------------------------
// fc2 reduce: out = x1 + bias + sum over 4 K-slice partials (all fp32)
// ---------------------------------------------------------------------------
__global__ __launch_bounds__(256) void fc2_red(const float* __restrict__ part,
    const float* __restrict__ x1, const float* __restrict__ bias,
    float* __restrict__ out) {
  int i = (blockIdx.x * 256 + threadIdx.x) * 4;     // over 4096*1024 elems
  f32x4 s = *(const f32x4*)(part + i);
  s += *(const f32x4*)(part + 4194304 + i);
  s += *(const f32x4*)(part + 2 * 4194304 + i);
  s += *(const f32x4*)(part + 3 * 4194304 + i);
  s += *(const f32x4*)(x1 + i);
  s += *(const f32x4*)(bias + (i & 1023));
  *(f32x4*)(out + i) = s;
}

// ---------------------------------------------------------------------------
// m97-structure GEMM (kept for proj + fallbacks)
// ---------------------------------------------------------------------------
template<int ACT, int HASRES, typename TO>
__global__ __launch_bounds__(256) void gemm_bt(const bf16* __restrict__ A,
    const bf16* __restrict__ W, const float* __restrict__ bias,
    const float* __restrict__ res, TO* __restrict__ out, int M, int N, int K) {
  __shared__ bf16 As[128 * 32];
  __shared__ bf16 Bs[128 * 32];
  int tid = threadIdx.x;
  int w = tid >> 6, l = tid & 63;
  int lr = l & 15, lg = l >> 4;
  int wm = w >> 1, wn = w & 1;
  int rowBase = blockIdx.y * 128;
  int colBase = blockIdx.x * 128;
  f32x4 acc[4][4];
  const f32x4 fz = {0.f, 0.f, 0.f, 0.f};
  #pragma unroll
  for (int i = 0; i < 4; ++i)
    #pragma unroll
    for (int j = 0; j < 4; ++j) acc[i][j] = fz;

  for (int kt = 0; kt < K; kt += 32) {
    __syncthreads();
    #pragma unroll
    for (int j = 0; j < 2; ++j) {
      int u = (w * 2 + j) * 64 + l;
      int r = u >> 2, cb = (u & 3) * 8;
      GLOAD_LDS16(A + (size_t)(rowBase + r) * K + kt + cb, As + (w * 2 + j) * 512);
      GLOAD_LDS16(W + (size_t)(colBase + r) * K + kt + cb, Bs + (w * 2 + j) * 512);
    }
    __syncthreads();
    bf16x8 af[4], bfr[4];
    #pragma unroll
    for (int mi = 0; mi < 4; ++mi)
      af[mi] = *(const bf16x8*)(As + (wm * 64 + mi * 16 + lr) * 32 + lg * 8);
    #pragma unroll
    for (int ni = 0; ni < 4; ++ni)
      bfr[ni] = *(const bf16x8*)(Bs + (wn * 64 + ni * 16 + lr) * 32 + lg * 8);
    #pragma unroll
    for (int mi = 0; mi < 4; ++mi)
      #pragma unroll
      for (int ni = 0; ni < 4; ++ni)
        acc[mi][ni] = __builtin_amdgcn_mfma_f32_16x16x32_bf16(af[mi], bfr[ni], acc[mi][ni], 0, 0, 0);
  }

  #pragma unroll
  for (int ni = 0; ni < 4; ++ni) {
    int col = colBase + wn * 64 + ni * 16 + lr;
    float bv = bias[col];
    #pragma unroll
    for (int mi = 0; mi < 4; ++mi) {
      #pragma unroll
      for (int jj = 0; jj < 4; ++jj) {
        int row2 = rowBase + wm * 64 + mi * 16 + lg * 4 + jj;
        float v = acc[mi][ni][jj] + bv;
        if constexpr (ACT == 1) v = 0.5f * v * (1.f + erff(v * 0.70710678118f));
        if constexpr (HASRES)   v += res[(size_t)row2 * N + col];
        out[(size_t)row2 * N + col] = (TO)v;
      }
    }
  }
}

// ---------------------------------------------------------------------------
// Flash attention. SPLIT=0: full KV (grid 1024), bf16 normalized out.
// SPLIT=1: half KV per block (grid 2048), fp32 unnormalized partial + (m,s).
// Swapped QK^T, exp2-domain online softmax, defer-max, setprio, T14 prefetch.
// ---------------------------------------------------------------------------
template<int SPLIT>
__global__ __launch_bounds__(256) void attn_kernel(const bf16* __restrict__ qkv,
    bf16* __restrict__ o, float* __restrict__ opart, float2* __restrict__ ms) {
  const int Nn = 2048, C3 = 3072;
  int tid = threadIdx.x, w = tid >> 6, l = tid & 63, lr = l & 15, lg = l >> 4;
  int lin = blockIdx.x;
  int half, qb, bh;
  if constexpr (SPLIT) {
    int wg = (lin & 7) * 256 + (lin >> 3);
    half = wg >> 10;
    qb = wg & 31; bh = (wg >> 5) & 31;
  } else {
    int wg = (lin & 7) * 128 + (lin >> 3);
    half = 0; qb = wg & 31; bh = wg >> 5;
  }
  int b = bh >> 4, h = bh & 15;
  size_t hb = (size_t)b * Nn * C3 + h * 64;
  const bf16* Qp = qkv + hb;
  const bf16* Kp = qkv + hb + 1024;
  const bf16* Vp = qkv + hb + 2048;
  __shared__ bf16 Ks[64 * 64];
  __shared__ bf16 Vt[64 * 72];
  __shared__ bf16 Ps[4][16 * 64];

  int q0 = qb * 64 + w * 16;
  bf16x8 qf[2];
  #pragma unroll
  for (int kk = 0; kk < 2; ++kk) {
    bf16x8 t = *(const bf16x8*)(Qp + (size_t)(q0 + lr) * C3 + kk * 32 + lg * 8);
    #pragma unroll
    for (int e = 0; e < 8; ++e) qf[kk][e] = (bf16)((float)t[e] * 0.18033688f);
  }

  const f32x4 fz = {0.f, 0.f, 0.f, 0.f};
  f32x4 oa[4];
  #pragma unroll
  for (int c = 0; c < 4; ++c) oa[c] = fz;
  float mrow = -1e30f, srow = 0.f;

  int t0   = SPLIT ? half * 16 : 0;
  int tend = SPLIT ? t0 + 16 : Nn / 64;

  int kr0 = tid >> 3,         c80 = (tid & 7) * 8;
  int kr1 = (256 + tid) >> 3, c81 = (tid & 7) * 8;
  bf16x8 kreg0, kreg1, vreg0, vreg1;
  {
    size_t k0 = (size_t)t0 * 64;
    kreg0 = *(const bf16x8*)(Kp + (k0 + kr0) * C3 + c80);
    kreg1 = *(const bf16x8*)(Kp + (k0 + kr1) * C3 + c81);
    vreg0 = *(const bf16x8*)(Vp + (k0 + l) * C3 + w * 8);
    vreg1 = *(const bf16x8*)(Vp + (k0 + l) * C3 + (4 + w) * 8);
  }

  for (int t = t0; t < tend; ++t) {
    __syncthreads();
    *(bf16x8*)((char*)Ks + kr0 * 128 + ((c80 * 2) ^ ((kr0 & 7) << 4))) = kreg0;
    *(bf16x8*)((char*)Ks + kr1 * 128 + ((c81 * 2) ^ ((kr1 & 7) << 4))) = kreg1;
    #pragma unroll
    for (int e = 0; e < 8; ++e) Vt[(w * 8 + e) * 72 + l]       = vreg0[e];
    #pragma unroll
    for (int e = 0; e < 8; ++e) Vt[((4 + w) * 8 + e) * 72 + l] = vreg1[e];
    __syncthreads();
    if (t + 1 < tend) {
      size_t kn = (size_t)(t + 1) * 64;
      kreg0 = *(const bf16x8*)(Kp + (kn + kr0) * C3 + c80);
      kreg1 = *(const bf16x8*)(Kp + (kn + kr1) * C3 + c81);
      vreg0 = *(const bf16x8*)(Vp + (kn + l) * C3 + w * 8);
      vreg1 = *(const bf16x8*)(Vp + (kn + l) * C3 + (4 + w) * 8);
    }

    f32x4 sc[4];
    __builtin_amdgcn_s_setprio(1);
    #pragma unroll
    for (int c = 0; c < 4; ++c) {
      f32x4 acm = fz;
      #pragma unroll
      for (int kk = 0; kk < 2; ++kk) {
        int krow = c * 16 + lr;
        bf16x8 kf = *(const bf16x8*)((char*)Ks + krow * 128 +
                                     ((kk * 64 + lg * 16) ^ ((krow & 7) << 4)));
        acm = __builtin_amdgcn_mfma_f32_16x16x32_bf16(kf, qf[kk], acm, 0, 0, 0);
      }
      sc[c] = acm;
    }
    __builtin_amdgcn_s_setprio(0);

    float m0 = fmaxf(fmaxf(sc[0][0], sc[0][1]), fmaxf(sc[0][2], sc[0][3]));
    float m1 = fmaxf(fmaxf(sc[1][0], sc[1][1]), fmaxf(sc[1][2], sc[1][3]));
    float m2 = fmaxf(fmaxf(sc[2][0], sc[2][1]), fmaxf(sc[2][2], sc[2][3]));
    float m3 = fmaxf(fmaxf(sc[3][0], sc[3][1]), fmaxf(sc[3][2], sc[3][3]));
    float mt = fmaxf(fmaxf(m0, m1), fmaxf(m2, m3));
    mt = fmaxf(mt, __shfl_xor(mt, 16));
    mt = fmaxf(mt, __shfl_xor(mt, 32));
    if (!__all(mt - mrow <= 8.f)) {
      float mn = fmaxf(mrow, mt);
      float al = exp2f(mrow - mn);
      mrow = mn;
      srow *= al;
      #pragma unroll
      for (int c = 0; c < 4; ++c)
        #pragma unroll
        for (int j = 0; j < 4; ++j) oa[c][j] *= al;
    }
    float p[4][4];
    float rs = 0.f;
    #pragma unroll
    for (int c = 0; c < 4; ++c) {
      float r0 = exp2f(sc[c][0] - mrow), r1 = exp2f(sc[c][1] - mrow);
      float r2 = exp2f(sc[c][2] - mrow), r3 = exp2f(sc[c][3] - mrow);
      p[c][0] = r0; p[c][1] = r1; p[c][2] = r2; p[c][3] = r3;
      rs += (r0 + r1) + (r2 + r3);
    }
    rs += __shfl_xor(rs, 16);
    rs += __shfl_xor(rs, 32);
    srow += rs;

    #pragma unroll
    for (int c = 0; c < 4; ++c) {
      bf16x4 pk;
      #pragma unroll
      for (int j = 0; j < 4; ++j) pk[j] = (bf16)p[c][j];
      *(bf16x4*)((char*)Ps[w] + lr * 128 + ((c * 32 + lg * 8) ^ ((lr & 7) << 4))) = pk;
    }
    bf16x8 pb[2];
    #pragma unroll
    for (int kk = 0; kk < 2; ++kk)
      pb[kk] = *(const bf16x8*)((char*)Ps[w] + lr * 128 +
                                ((kk * 64 + lg * 16) ^ ((lr & 7) << 4)));
    __builtin_amdgcn_s_setprio(1);
    #pragma unroll
    for (int cd = 0; cd < 4; ++cd)
      #pragma unroll
      for (int kk = 0; kk < 2; ++kk) {
        bf16x8 vf = *(const bf16x8*)(Vt + (cd * 16 + lr) * 72 + kk * 32 + lg * 8);
        oa[cd] = __builtin_amdgcn_mfma_f32_16x16x32_bf16(vf, pb[kk], oa[cd], 0, 0, 0);
      }
    __builtin_amdgcn_s_setprio(0);
  }

  size_t qr = (size_t)q0 + lr;
  if constexpr (SPLIT) {
    float* op = opart + (size_t)half * 4194304 + ((size_t)(b * Nn) + qr) * 1024 + h * 64;
    #pragma unroll
    for (int cd = 0; cd < 4; ++cd) {
      f32x4 v = oa[cd];
      *(f32x4*)(op + cd * 16 + lg * 4) = v;
    }
    if (lg == 0) ms[((size_t)(half * 32 + bh)) * 2048 + qr] = make_float2(mrow, srow);
  } else {
    float inv = 1.f / srow;
    #pragma unroll
    for (int cd = 0; cd < 4; ++cd)
      #pragma unroll
      for (int j = 0; j < 4; ++j)
        o[((size_t)b * Nn + qr) * 1024 + h * 64 + cd * 16 + lg * 4 + j] =
            (bf16)(oa[cd][j] * inv);
  }
}

// ---------------------------------------------------------------------------
// attn merge: combine two KV-half partials via LSE weights -> bf16 ov
// ---------------------------------------------------------------------------
__global__ __launch_bounds__(256) void attn_merge(const float* __restrict__ opart,
    const float2* __restrict__ ms, bf16* __restrict__ o) {
  int i4 = blockIdx.x * 256 + threadIdx.x;          // 1,048,576 groups of 4
  int d4 = i4 & 15, h = (i4 >> 4) & 15, q = (i4 >> 8) & 2047, b = i4 >> 19;
  int bh = b * 16 + h;
  float2 s0 = ms[(size_t)bh * 2048 + q];
  float2 s1 = ms[(size_t)(32 + bh) * 2048 + q];
  float m = fmaxf(s0.x, s1.x);
  float w0 = exp2f(s0.x - m), w1 = exp2f(s1.x - m);
  float inv = 1.f / (s0.y * w0 + s1.y * w1);
  size_t off = (((size_t)b * 2048 + q) * 16 + h) * 64 + d4 * 4;
  f32x4 a0 = *(const f32x4*)(opart + off);
  f32x4 a1 = *(const f32x4*)(opart + 4194304 + off);
  bf16x4 ov;
  #pragma unroll
  for (int e = 0; e < 4; ++e) ov[e] = (bf16)((a0[e] * w0 + a1[e] * w1) * inv);
  *(bf16x4*)(o + off) = ov;
}

// ---------------------------------------------------------------------------
extern "C" void kernel_launch(void* const* d_in, const int* in_sizes, int n_in,
                              void* d_out, int out_size, void* d_ws, size_t ws_size,
                              hipStream_t stream) {
  (void)in_sizes; (void)n_in; (void)out_size;
  const float* x     = (const float*)d_in[0];
  const float* ln1g  = (const float*)d_in[1];
  const float* ln1b  = (const float*)d_in[2];
  const float* qkvw  = (const float*)d_in[3];
  const float* qkvb  = (const float*)d_in[4];
  const float* projw = (const float*)d_in[5];
  const float* projb = (const float*)d_in[6];
  const float* ln2g  = (const float*)d_in[7];
  const float* ln2b  = (const float*)d_in[8];
  const float* fc1w  = (const float*)d_in[9];
  const float* fc1b  = (const float*)d_in[10];
  const float* fc2w  = (const float*)d_in[11];
  const float* fc2b  = (const float*)d_in[12];

  char* ws = (char*)d_ws;
  bf16*  qkvw_h = (bf16*)(ws);                    // [0,  6M)
  bf16*  projw_h= (bf16*)(ws + (6ull  << 20));    // [6,  8M)
  bf16*  fc1w_h = (bf16*)(ws + (8ull  << 20));    // [8, 16M)
  bf16*  fc2w_h = (bf16*)(ws + (16ull << 20));    // [16,24M)
  bf16*  h1     = (bf16*)(ws + (24ull << 20));    // [24,32M)  (reused for h2)
  bf16*  qkv    = (bf16*)(ws + (32ull << 20));    // [32,64M)  (reused for ffn)
  bf16*  ov     = (bf16*)(ws + (64ull << 20));    // [64,72M)
  float* x1     = (float*)(ws + (72ull << 20));   // [72,88M)  fp32 residual trunk
  float* opart  = (float*)(ws + (96ull << 20));   // [96, 130M) 2x fp32 O partial
  float2* msb   = (float2*)(ws + (130ull << 20)); // [130,131M)
  float* fc2p   = (float*)(ws + (132ull << 20));  // [132,196M) 4x fp32 fc2 partial
  bf16*  h2  = h1;
  bf16*  ffn = qkv;
  bool big = ws_size >= (196ull << 20);

  const int M = 4096;
  prep<<<dim3(12288 + 1024), 256, 0, stream>>>(qkvw, projw, fc1w, fc2w,
      qkvw_h, projw_h, fc1w_h, fc2w_h, x, ln1g, ln1b, h1);
  gemm256<0, 1, bf16><<<dim3(192), dim3(512), 0, stream>>>(
      h1, qkvw_h, qkvb, qkv, 1024, 3072, 1024, 12, 0);
  if (big) {
    attn_kernel<1><<<dim3(2048), 256, 0, stream>>>(qkv, nullptr, opart, msb);
    attn_merge<<<dim3(4096), 256, 0, stream>>>(opart, msb, ov);
  } else {
    attn_kernel<0><<<dim3(1024), 256, 0, stream>>>(qkv, ov, nullptr, nullptr);
  }
  gemm_bt<0, 1, float><<<dim3(1024 / 128, M / 128), 256, 0, stream>>>(
      ov, projw_h, projb, x, x1, M, 1024, 1024);
  ln_f32<<<dim3(M / 4), 256, 0, stream>>>(x1, ln2g, ln2b, h2);
  gemm256<1, 1, bf16><<<dim3(256), dim3(512), 0, stream>>>(
      h2, fc1w_h, fc1b, ffn, 1024, 4096, 1024, 16, 0);
  if (big) {
    gemm256<0, 0, float><<<dim3(64, 4), dim3(512), 0, stream>>>(
        ffn, fc2w_h, nullptr, fc2p, 4096, 1024, 1024, 4, 4194304ull);
    fc2_red<<<dim3(4096), 256, 0, stream>>>(fc2p, x1, fc2b, (float*)d_out);
  } else {
    gemm_bt<0, 1, float><<<dim3(1024 / 128, M / 128), 256, 0, stream>>>(
        ffn, fc2w_h, fc2b, x1, (float*)d_out, M, 1024, 4096);
  }
}

// Round 7
// 279.265 us; speedup vs baseline: 1.3416x; 1.0715x over previous
//
#include <hip/hip_runtime.h>
#include <hip/hip_bf16.h>
#include <math.h>

typedef __bf16 bf16;
typedef __bf16 bf16x8 __attribute__((ext_vector_type(8)));
typedef __bf16 bf16x4 __attribute__((ext_vector_type(4)));
typedef float  f32x4  __attribute__((ext_vector_type(4)));

typedef __attribute__((address_space(1))) void gvoid;
typedef __attribute__((address_space(3))) void lvoid;
#define GLOAD_LDS16(gp, lp) __builtin_amdgcn_global_load_lds((gvoid*)(gp), (lvoid*)(lp), 16, 0, 0)

// ---------------------------------------------------------------------------
// prep: fused weight fp32->bf16 conversion (blocks 0..12287) + LN1 (12288+)
// ---------------------------------------------------------------------------
__global__ __launch_bounds__(256) void prep(
    const float* __restrict__ qkvw, const float* __restrict__ projw,
    const float* __restrict__ fc1w, const float* __restrict__ fc2w,
    bf16* __restrict__ qkvw_h, bf16* __restrict__ projw_h,
    bf16* __restrict__ fc1w_h, bf16* __restrict__ fc2w_h,
    const float* __restrict__ x, const float* __restrict__ g,
    const float* __restrict__ b, bf16* __restrict__ h1) {
  int blk = blockIdx.x;
  if (blk < 12288) {
    const float* in; bf16* out; int base;
    if (blk < 3072)      { in = qkvw; out = qkvw_h; base = blk; }
    else if (blk < 4096) { in = projw; out = projw_h; base = blk - 3072; }
    else if (blk < 8192) { in = fc1w; out = fc1w_h; base = blk - 4096; }
    else                 { in = fc2w; out = fc2w_h; base = blk - 8192; }
    int i = (base * 256 + threadIdx.x) * 4;
    f32x4 v = *(const f32x4*)(in + i);
    bf16x4 o;
    #pragma unroll
    for (int e = 0; e < 4; ++e) o[e] = (bf16)v[e];
    *(bf16x4*)(out + i) = o;
    return;
  }
  int w = threadIdx.x >> 6, l = threadIdx.x & 63;
  size_t row = (size_t)(blk - 12288) * 4 + w;
  const float* xr = x + row * 1024;
  float f[16];
  #pragma unroll
  for (int c = 0; c < 4; ++c) {
    f32x4 v = *(const f32x4*)(xr + c * 256 + l * 4);
    #pragma unroll
    for (int e = 0; e < 4; ++e) f[c * 4 + e] = v[e];
  }
  float s = 0.f, ss = 0.f;
  #pragma unroll
  for (int e = 0; e < 16; ++e) { s += f[e]; ss += f[e] * f[e]; }
  #pragma unroll
  for (int d = 1; d < 64; d <<= 1) { s += __shfl_xor(s, d); ss += __shfl_xor(ss, d); }
  float mean = s * (1.f / 1024.f);
  float var  = ss * (1.f / 1024.f) - mean * mean;
  float rstd = rsqrtf(var + 1e-5f);
  #pragma unroll
  for (int c = 0; c < 4; ++c) {
    f32x4 gv = *(const f32x4*)(g + c * 256 + l * 4);
    f32x4 bv = *(const f32x4*)(b + c * 256 + l * 4);
    bf16x4 ov;
    #pragma unroll
    for (int e = 0; e < 4; ++e)
      ov[e] = (bf16)((f[c * 4 + e] - mean) * rstd * gv[e] + bv[e]);
    *(bf16x4*)(h1 + row * 1024 + c * 256 + l * 4) = ov;
  }
}

// ---------------------------------------------------------------------------
// LayerNorm standalone (for LN2): fp32 in -> bf16 out.
// ---------------------------------------------------------------------------
__global__ __launch_bounds__(256) void ln_f32(const float* __restrict__ x,
    const float* __restrict__ g, const float* __restrict__ b, bf16* __restrict__ out) {
  int w = threadIdx.x >> 6, l = threadIdx.x & 63;
  size_t row = (size_t)blockIdx.x * 4 + w;
  const float* xr = x + row * 1024;
  float f[16];
  #pragma unroll
  for (int c = 0; c < 4; ++c) {
    f32x4 v = *(const f32x4*)(xr + c * 256 + l * 4);
    #pragma unroll
    for (int e = 0; e < 4; ++e) f[c * 4 + e] = v[e];
  }
  float s = 0.f, ss = 0.f;
  #pragma unroll
  for (int e = 0; e < 16; ++e) { s += f[e]; ss += f[e] * f[e]; }
  #pragma unroll
  for (int d = 1; d < 64; d <<= 1) { s += __shfl_xor(s, d); ss += __shfl_xor(ss, d); }
  float mean = s * (1.f / 1024.f);
  float var  = ss * (1.f / 1024.f) - mean * mean;
  float rstd = rsqrtf(var + 1e-5f);
  #pragma unroll
  for (int c = 0; c < 4; ++c) {
    f32x4 gv = *(const f32x4*)(g + c * 256 + l * 4);
    f32x4 bv = *(const f32x4*)(b + c * 256 + l * 4);
    bf16x4 ov;
    #pragma unroll
    for (int e = 0; e < 4; ++e)
      ov[e] = (bf16)((f[c * 4 + e] - mean) * rstd * gv[e] + bv[e]);
    *(bf16x4*)(out + row * 1024 + c * 256 + l * 4) = ov;
  }
}

// ---------------------------------------------------------------------------
// 8-phase 256x256 GEMM (T2+T3+T4+T5). Generalized: lda, klen, K-slice via
// blockIdx.y, TO output, HASBIAS. Sync schedule = r5-verified template.
// ---------------------------------------------------------------------------
#define SWZ(tp) ((tp) ^ ((((tp) >> 9) & 1) << 5))
#define STAGE(buf, op, half, kt_) do { \
    const char* gp_ = (const char*)((op) ? Wp : Ap); \
    int t0_ = (op) ? colBase : rowBase; \
    const int P_ = (op) ? 12 : 13; \
    _Pragma("unroll") for (int s_ = 0; s_ < 2; ++s_) { \
      int b14_ = w * 2048 + s_ * 1024; \
      int tb_ = ((b14_ >> P_) << (P_ + 1)) | ((half) << P_) | (b14_ & ((1 << P_) - 1)); \
      int tq_ = SWZ(tb_ + l * 16); \
      GLOAD_LDS16(gp_ + ((size_t)(t0_ + (tq_ >> 7)) * lda + (size_t)(kt_) * 64) * 2 + (tq_ & 127), \
                  smbase + (buf) * 65536 + (op) * 32768 + tb_); \
    } \
  } while (0)
#define LDA(buf, mi, kk) (*(const bf16x8*)(smbase + (buf) * 65536 + \
    SWZ((wm * 128 + (mi) * 16 + lr) * 128 + (kk) * 64 + lg * 16)))
#define LDB(buf, ni, kk) (*(const bf16x8*)(smbase + (buf) * 65536 + 32768 + \
    SWZ((wn * 64 + (ni) * 16 + lr) * 128 + (kk) * 64 + lg * 16)))
#define RD_A(buf, MI0) { _Pragma("unroll") for (int i_ = 0; i_ < 4; ++i_) \
    _Pragma("unroll") for (int k_ = 0; k_ < 2; ++k_) a[i_][k_] = LDA(buf, (MI0) + i_, k_); }
#define RD_B(buf, NI0) { _Pragma("unroll") for (int j_ = 0; j_ < 2; ++j_) \
    _Pragma("unroll") for (int k_ = 0; k_ < 2; ++k_) bq[j_][k_] = LDB(buf, (NI0) + j_, k_); }
#define MFMA16(MI0, NI0) do { __builtin_amdgcn_s_setprio(1); \
    _Pragma("unroll") for (int i_ = 0; i_ < 4; ++i_) \
    _Pragma("unroll") for (int j_ = 0; j_ < 2; ++j_) \
    _Pragma("unroll") for (int k_ = 0; k_ < 2; ++k_) \
      acc[(MI0) + i_][(NI0) + j_] = __builtin_amdgcn_mfma_f32_16x16x32_bf16( \
          a[i_][k_], bq[j_][k_], acc[(MI0) + i_][(NI0) + j_], 0, 0, 0); \
    __builtin_amdgcn_s_setprio(0); } while (0)
#define BARX() __builtin_amdgcn_s_barrier()
#define LGK0() asm volatile("s_waitcnt lgkmcnt(0)")
#define VM4()  asm volatile("s_waitcnt vmcnt(4)")

template<int ACT, int HASBIAS, typename TO>
__global__ __launch_bounds__(512, 2) void gemm256(const bf16* __restrict__ Ap,
    const bf16* __restrict__ Wp, const float* __restrict__ bias,
    TO* __restrict__ out, int lda, int N, int klen, int nbx, size_t outSlice) {
  __shared__ bf16 smem_[2][2][256 * 64];
  char* smbase = (char*)smem_;
  int tid = threadIdx.x, w = tid >> 6, l = tid & 63, lr = l & 15, lg = l >> 4;
  int wm = w >> 2, wn = w & 3;
  int q = gridDim.x >> 3;                       // grid.x % 8 == 0 for all our shapes
  int wg = ((int)blockIdx.x & 7) * q + ((int)blockIdx.x >> 3);
  int rowBase = (wg / nbx) * 256, colBase = (wg % nbx) * 256;
  Ap += (size_t)blockIdx.y * klen;
  Wp += (size_t)blockIdx.y * klen;
  out += (size_t)blockIdx.y * outSlice;

  f32x4 acc[8][4];
  const f32x4 fz = {0.f, 0.f, 0.f, 0.f};
  #pragma unroll
  for (int i = 0; i < 8; ++i)
    #pragma unroll
    for (int j = 0; j < 4; ++j) acc[i][j] = fz;
  bf16x8 a[4][2], bq[2][2];
  int nkt = klen >> 6;

  STAGE(0, 0, 0, 0); STAGE(0, 1, 0, 0); STAGE(0, 0, 1, 0); STAGE(0, 1, 1, 0);
  STAGE(1, 1, 0, 1); STAGE(1, 0, 1, 1);
  VM4(); BARX();

  for (int t = 0; t < nkt; t += 2) {
    int t1 = t + 1;
    int t2 = t + 2 < nkt ? t + 2 : nkt - 1;
    int t3 = t + 3 < nkt ? t + 3 : nkt - 1;
    RD_A(0, 0); RD_B(0, 0);
    STAGE(1, 0, 0, t1); STAGE(1, 1, 1, t1);
    BARX(); LGK0(); MFMA16(0, 0); BARX();
    RD_A(0, 4);
    BARX(); LGK0(); MFMA16(4, 0); BARX();
    RD_B(0, 2);
    STAGE(0, 1, 0, t2);
    BARX(); LGK0(); MFMA16(4, 2); BARX();
    RD_A(0, 0);
    STAGE(0, 0, 1, t2);
    VM4();
    BARX(); LGK0(); MFMA16(0, 2); BARX();
    RD_A(1, 0); RD_B(1, 0);
    STAGE(0, 0, 0, t2); STAGE(0, 1, 1, t2);
    BARX(); LGK0(); MFMA16(0, 0); BARX();
    RD_A(1, 4);
    BARX(); LGK0(); MFMA16(4, 0); BARX();
    RD_B(1, 2);
    STAGE(1, 1, 0, t3);
    BARX(); LGK0(); MFMA16(4, 2); BARX();
    RD_A(1, 0);
    STAGE(1, 0, 1, t3);
    VM4();
    BARX(); LGK0(); MFMA16(0, 2); BARX();
  }

  #pragma unroll
  for (int ni = 0; ni < 4; ++ni) {
    int col = colBase + wn * 64 + ni * 16 + lr;
    float bv = HASBIAS ? bias[col] : 0.f;
    #pragma unroll
    for (int mi = 0; mi < 8; ++mi) {
      #pragma unroll
      for (int jj = 0; jj < 4; ++jj) {
        int row2 = rowBase + wm * 128 + mi * 16 + lg * 4 + jj;
        float v = acc[mi][ni][jj] + bv;
        if constexpr (ACT == 1) v = 0.5f * v * (1.f + erff(v * 0.70710678118f));
        out[(size_t)row2 * N + col] = (TO)v;
      }
    }
  }
}

// ---------------------------------------------------------------------------
// fc2 reduce: out = x1 + bias + sum of 4 bf16 K-slice partials
// ---------------------------------------------------------------------------
__global__ __launch_bounds__(256) void fc2_red(const bf16* __restrict__ part,
    const float* __restrict__ x1, const float* __restrict__ bias,
    float* __restrict__ out) {
  int i = (blockIdx.x * 256 + threadIdx.x) * 4;     // over 4096*1024 elems
  f32x4 s = *(const f32x4*)(x1 + i);
  s += *(const f32x4*)(bias + (i & 1023));
  #pragma unroll
  for (int k = 0; k < 4; ++k) {
    bf16x4 pv = *(const bf16x4*)(part + (size_t)k * 4194304 + i);
    #pragma unroll
    for (int e = 0; e < 4; ++e) s[e] += (float)pv[e];
  }
  *(f32x4*)(out + i) = s;
}

// ---------------------------------------------------------------------------
// m97-structure GEMM (kept for proj)
// ---------------------------------------------------------------------------
template<int ACT, int HASRES, typename TO>
__global__ __launch_bounds__(256) void gemm_bt(const bf16* __restrict__ A,
    const bf16* __restrict__ W, const float* __restrict__ bias,
    const float* __restrict__ res, TO* __restrict__ out, int M, int N, int K) {
  __shared__ bf16 As[128 * 32];
  __shared__ bf16 Bs[128 * 32];
  int tid = threadIdx.x;
  int w = tid >> 6, l = tid & 63;
  int lr = l & 15, lg = l >> 4;
  int wm = w >> 1, wn = w & 1;
  int rowBase = blockIdx.y * 128;
  int colBase = blockIdx.x * 128;
  f32x4 acc[4][4];
  const f32x4 fz = {0.f, 0.f, 0.f, 0.f};
  #pragma unroll
  for (int i = 0; i < 4; ++i)
    #pragma unroll
    for (int j = 0; j < 4; ++j) acc[i][j] = fz;

  for (int kt = 0; kt < K; kt += 32) {
    __syncthreads();
    #pragma unroll
    for (int j = 0; j < 2; ++j) {
      int u = (w * 2 + j) * 64 + l;
      int r = u >> 2, cb = (u & 3) * 8;
      GLOAD_LDS16(A + (size_t)(rowBase + r) * K + kt + cb, As + (w * 2 + j) * 512);
      GLOAD_LDS16(W + (size_t)(colBase + r) * K + kt + cb, Bs + (w * 2 + j) * 512);
    }
    __syncthreads();
    bf16x8 af[4], bfr[4];
    #pragma unroll
    for (int mi = 0; mi < 4; ++mi)
      af[mi] = *(const bf16x8*)(As + (wm * 64 + mi * 16 + lr) * 32 + lg * 8);
    #pragma unroll
    for (int ni = 0; ni < 4; ++ni)
      bfr[ni] = *(const bf16x8*)(Bs + (wn * 64 + ni * 16 + lr) * 32 + lg * 8);
    #pragma unroll
    for (int mi = 0; mi < 4; ++mi)
      #pragma unroll
      for (int ni = 0; ni < 4; ++ni)
        acc[mi][ni] = __builtin_amdgcn_mfma_f32_16x16x32_bf16(af[mi], bfr[ni], acc[mi][ni], 0, 0, 0);
  }

  #pragma unroll
  for (int ni = 0; ni < 4; ++ni) {
    int col = colBase + wn * 64 + ni * 16 + lr;
    float bv = bias[col];
    #pragma unroll
    for (int mi = 0; mi < 4; ++mi) {
      #pragma unroll
      for (int jj = 0; jj < 4; ++jj) {
        int row2 = rowBase + wm * 64 + mi * 16 + lg * 4 + jj;
        float v = acc[mi][ni][jj] + bv;
        if constexpr (ACT == 1) v = 0.5f * v * (1.f + erff(v * 0.70710678118f));
        if constexpr (HASRES)   v += res[(size_t)row2 * N + col];
        out[(size_t)row2 * N + col] = (TO)v;
      }
    }
  }
}

// ---------------------------------------------------------------------------
// Flash attention (r7): full-KV, swapped QK^T, exp2 softmax, defer-max,
// setprio, T14 prefetch, XCD swizzle. ALL LDS addresses hoisted to registers
// before the loop; global K/V pointers increment (no per-tile 64b mul).
// ---------------------------------------------------------------------------
__global__ __launch_bounds__(256) void attn_kernel(const bf16* __restrict__ qkv,
                                                   bf16* __restrict__ o) {
  const int Nn = 2048, C3 = 3072;
  int tid = threadIdx.x, w = tid >> 6, l = tid & 63, lr = l & 15, lg = l >> 4;
  int lin = blockIdx.x;
  int wg = (lin & 7) * 128 + (lin >> 3);
  int qb = wg & 31, bh = wg >> 5;
  int b = bh >> 4, h = bh & 15;
  size_t hb = (size_t)b * Nn * C3 + h * 64;
  const bf16* Qp = qkv + hb;
  __shared__ bf16 Ks[64 * 64];
  __shared__ bf16 Vt[64 * 72];
  __shared__ bf16 Ps[4][16 * 64];

  int q0 = qb * 64 + w * 16;
  bf16x8 qf[2];
  #pragma unroll
  for (int kk = 0; kk < 2; ++kk) {
    bf16x8 t = *(const bf16x8*)(Qp + (size_t)(q0 + lr) * C3 + kk * 32 + lg * 8);
    #pragma unroll
    for (int e = 0; e < 8; ++e) qf[kk][e] = (bf16)((float)t[e] * 0.18033688f);
  }

  // ---- hoisted loop-invariant addresses ----
  int sz = (lr & 7) << 4;                         // XOR swizzle for row lr
  int kr0 = tid >> 3, c80 = (tid & 7) * 8;
  int kr1 = kr0 + 32;
  char* ksw0 = (char*)Ks + kr0 * 128 + ((c80 * 2) ^ ((kr0 & 7) << 4));
  char* ksw1 = (char*)Ks + kr1 * 128 + ((c80 * 2) ^ ((kr1 & 7) << 4));
  bf16* vtw0 = Vt + (w * 8) * 72 + l;             // + e*72 (imm)
  bf16* vtw1 = Vt + (32 + w * 8) * 72 + l;
  const char* ksr0 = (const char*)Ks + lr * 128 + ((lg * 16) ^ sz);       // + c*2048
  const char* ksr1 = (const char*)Ks + lr * 128 + ((64 + lg * 16) ^ sz);
  char* psb = (char*)Ps[w] + lr * 128;
  char* psw0 = psb + ((lg * 8) ^ sz);
  char* psw1 = psb + ((32 + lg * 8) ^ sz);
  char* psw2 = psb + ((64 + lg * 8) ^ sz);
  char* psw3 = psb + ((96 + lg * 8) ^ sz);
  const char* psr0 = psb + ((lg * 16) ^ sz);
  const char* psr1 = psb + ((64 + lg * 16) ^ sz);
  const bf16* vtr = Vt + lr * 72 + lg * 8;        // + cd*1152 + kk*32 (imm)

  const bf16* kp0 = qkv + hb + 1024 + (size_t)kr0 * C3 + c80;
  const bf16* kp1 = qkv + hb + 1024 + (size_t)kr1 * C3 + c80;
  const bf16* vp0 = qkv + hb + 2048 + (size_t)l * C3 + w * 8;
  const bf16* vp1 = vp0 + 32;
  const int step = 64 * C3;

  const f32x4 fz = {0.f, 0.f, 0.f, 0.f};
  f32x4 oa[4];
  #pragma unroll
  for (int c = 0; c < 4; ++c) oa[c] = fz;
  float mrow = -1e30f, srow = 0.f;

  bf16x8 kreg0 = *(const bf16x8*)kp0; kp0 += step;
  bf16x8 kreg1 = *(const bf16x8*)kp1; kp1 += step;
  bf16x8 vreg0 = *(const bf16x8*)vp0; vp0 += step;
  bf16x8 vreg1 = *(const bf16x8*)vp1; vp1 += step;

  for (int t = 0; t < 32; ++t) {
    __syncthreads();
    *(bf16x8*)ksw0 = kreg0;
    *(bf16x8*)ksw1 = kreg1;
    #pragma unroll
    for (int e = 0; e < 8; ++e) vtw0[e * 72] = vreg0[e];
    #pragma unroll
    for (int e = 0; e < 8; ++e) vtw1[e * 72] = vreg1[e];
    __syncthreads();
    if (t < 31) {                               // T14: prefetch next tile
      kreg0 = *(const bf16x8*)kp0; kp0 += step;
      kreg1 = *(const bf16x8*)kp1; kp1 += step;
      vreg0 = *(const bf16x8*)vp0; vp0 += step;
      vreg1 = *(const bf16x8*)vp1; vp1 += step;
    }

    // S^T = K Q^T (log2-scaled): lane holds S[q=lr][k=16c+4lg+j]
    f32x4 sc[4];
    __builtin_amdgcn_s_setprio(1);
    #pragma unroll
    for (int c = 0; c < 4; ++c) {
      f32x4 acm = fz;
      acm = __builtin_amdgcn_mfma_f32_16x16x32_bf16(
          *(const bf16x8*)(ksr0 + c * 2048), qf[0], acm, 0, 0, 0);
      acm = __builtin_amdgcn_mfma_f32_16x16x32_bf16(
          *(const bf16x8*)(ksr1 + c * 2048), qf[1], acm, 0, 0, 0);
      sc[c] = acm;
    }
    __builtin_amdgcn_s_setprio(0);

    float m0 = fmaxf(fmaxf(sc[0][0], sc[0][1]), fmaxf(sc[0][2], sc[0][3]));
    float m1 = fmaxf(fmaxf(sc[1][0], sc[1][1]), fmaxf(sc[1][2], sc[1][3]));
    float m2 = fmaxf(fmaxf(sc[2][0], sc[2][1]), fmaxf(sc[2][2], sc[2][3]));
    float m3 = fmaxf(fmaxf(sc[3][0], sc[3][1]), fmaxf(sc[3][2], sc[3][3]));
    float mt = fmaxf(fmaxf(m0, m1), fmaxf(m2, m3));
    mt = fmaxf(mt, __shfl_xor(mt, 16));
    mt = fmaxf(mt, __shfl_xor(mt, 32));
    if (!__all(mt - mrow <= 8.f)) {
      float mn = fmaxf(mrow, mt);
      float al = exp2f(mrow - mn);
      mrow = mn;
      srow *= al;
      #pragma unroll
      for (int c = 0; c < 4; ++c)
        #pragma unroll
        for (int j = 0; j < 4; ++j) oa[c][j] *= al;
    }
    float p[4][4];
    float rs = 0.f;
    #pragma unroll
    for (int c = 0; c < 4; ++c) {
      float r0 = exp2f(sc[c][0] - mrow), r1 = exp2f(sc[c][1] - mrow);
      float r2 = exp2f(sc[c][2] - mrow), r3 = exp2f(sc[c][3] - mrow);
      p[c][0] = r0; p[c][1] = r1; p[c][2] = r2; p[c][3] = r3;
      rs += (r0 + r1) + (r2 + r3);
    }
    rs += __shfl_xor(rs, 16);
    rs += __shfl_xor(rs, 32);
    srow += rs;

    bf16x4 pk0, pk1, pk2, pk3;
    #pragma unroll
    for (int j = 0; j < 4; ++j) {
      pk0[j] = (bf16)p[0][j]; pk1[j] = (bf16)p[1][j];
      pk2[j] = (bf16)p[2][j]; pk3[j] = (bf16)p[3][j];
    }
    *(bf16x4*)psw0 = pk0; *(bf16x4*)psw1 = pk1;
    *(bf16x4*)psw2 = pk2; *(bf16x4*)psw3 = pk3;
    bf16x8 pb0 = *(const bf16x8*)psr0;
    bf16x8 pb1 = *(const bf16x8*)psr1;
    __builtin_amdgcn_s_setprio(1);
    #pragma unroll
    for (int cd = 0; cd < 4; ++cd) {
      oa[cd] = __builtin_amdgcn_mfma_f32_16x16x32_bf16(
          *(const bf16x8*)(vtr + cd * 1152), pb0, oa[cd], 0, 0, 0);
      oa[cd] = __builtin_amdgcn_mfma_f32_16x16x32_bf16(
          *(const bf16x8*)(vtr + cd * 1152 + 32), pb1, oa[cd], 0, 0, 0);
    }
    __builtin_amdgcn_s_setprio(0);
  }

  float inv = 1.f / srow;
  size_t qr = (size_t)q0 + lr;
  #pragma unroll
  for (int cd = 0; cd < 4; ++cd)
    #pragma unroll
    for (int j = 0; j < 4; ++j)
      o[((size_t)b * Nn + qr) * 1024 + h * 64 + cd * 16 + lg * 4 + j] =
          (bf16)(oa[cd][j] * inv);
}

// ---------------------------------------------------------------------------
extern "C" void kernel_launch(void* const* d_in, const int* in_sizes, int n_in,
                              void* d_out, int out_size, void* d_ws, size_t ws_size,
                              hipStream_t stream) {
  (void)in_sizes; (void)n_in; (void)out_size;
  const float* x     = (const float*)d_in[0];
  const float* ln1g  = (const float*)d_in[1];
  const float* ln1b  = (const float*)d_in[2];
  const float* qkvw  = (const float*)d_in[3];
  const float* qkvb  = (const float*)d_in[4];
  const float* projw = (const float*)d_in[5];
  const float* projb = (const float*)d_in[6];
  const float* ln2g  = (const float*)d_in[7];
  const float* ln2b  = (const float*)d_in[8];
  const float* fc1w  = (const float*)d_in[9];
  const float* fc1b  = (const float*)d_in[10];
  const float* fc2w  = (const float*)d_in[11];
  const float* fc2b  = (const float*)d_in[12];

  char* ws = (char*)d_ws;
  bf16*  qkvw_h = (bf16*)(ws);                    // [0,  6M)
  bf16*  projw_h= (bf16*)(ws + (6ull  << 20));    // [6,  8M)
  bf16*  fc1w_h = (bf16*)(ws + (8ull  << 20));    // [8, 16M)
  bf16*  fc2w_h = (bf16*)(ws + (16ull << 20));    // [16,24M)
  bf16*  h1     = (bf16*)(ws + (24ull << 20));    // [24,32M)  (reused for h2)
  bf16*  qkv    = (bf16*)(ws + (32ull << 20));    // [32,64M)  (reused for ffn)
  bf16*  ov     = (bf16*)(ws + (64ull << 20));    // [64,72M)
  float* x1     = (float*)(ws + (72ull << 20));   // [72,88M)  fp32 residual trunk
  bf16*  fc2p   = (bf16*)(ws + (96ull << 20));    // [96,128M) 4x bf16 fc2 partial
  bf16*  h2  = h1;
  bf16*  ffn = qkv;
  bool big = ws_size >= (160ull << 20);

  const int M = 4096;
  prep<<<dim3(12288 + 1024), 256, 0, stream>>>(qkvw, projw, fc1w, fc2w,
      qkvw_h, projw_h, fc1w_h, fc2w_h, x, ln1g, ln1b, h1);
  gemm256<0, 1, bf16><<<dim3(192), dim3(512), 0, stream>>>(
      h1, qkvw_h, qkvb, qkv, 1024, 3072, 1024, 12, 0);
  attn_kernel<<<dim3(1024), 256, 0, stream>>>(qkv, ov);
  gemm_bt<0, 1, float><<<dim3(1024 / 128, M / 128), 256, 0, stream>>>(
      ov, projw_h, projb, x, x1, M, 1024, 1024);
  ln_f32<<<dim3(M / 4), 256, 0, stream>>>(x1, ln2g, ln2b, h2);
  gemm256<1, 1, bf16><<<dim3(256), dim3(512), 0, stream>>>(
      h2, fc1w_h, fc1b, ffn, 1024, 4096, 1024, 16, 0);
  if (big) {
    gemm256<0, 0, bf16><<<dim3(64, 4), dim3(512), 0, stream>>>(
        ffn, fc2w_h, nullptr, fc2p, 4096, 1024, 1024, 4, 4194304ull);
    fc2_red<<<dim3(4096), 256, 0, stream>>>(fc2p, x1, fc2b, (float*)d_out);
  } else {
    gemm_bt<0, 1, float><<<dim3(1024 / 128, M / 128), 256, 0, stream>>>(
        ffn, fc2w_h, fc2b, x1, (float*)d_out, M, 1024, 4096);
  }
}